// Round 1
// baseline (1506.500 us; speedup 1.0000x reference)
//
#include <hip/hip_runtime.h>
#include <hip/hip_bf16.h>

#define N_NODES 100000
#define N_EDGES 3200000
#define F_IN    512
#define HID     256
#define C_OUT   40

typedef unsigned short u16;

__device__ __forceinline__ float bf2f(u16 u) {
    unsigned int x = ((unsigned int)u) << 16;
    return __uint_as_float(x);
}
__device__ __forceinline__ u16 f2bf(float f) {
    unsigned int x = __float_as_uint(f);
    return (u16)((x + 0x7fffu + ((x >> 16) & 1u)) >> 16);  // RNE
}

// ---------------- CSR build ----------------

__global__ void k_hist(const int* __restrict__ row, int* __restrict__ counts, int E) {
    int i = blockIdx.x * blockDim.x + threadIdx.x;
    int stride = gridDim.x * blockDim.x;
    for (; i < E; i += stride) atomicAdd(&counts[row[i]], 1);
}

__global__ void k_scan_block(const int* __restrict__ counts, int* __restrict__ bsum, int n) {
    int i = blockIdx.x * 256 + threadIdx.x;
    int v = (i < n) ? counts[i] : 0;
    for (int s = 32; s; s >>= 1) v += __shfl_xor(v, s);
    __shared__ int red[4];
    int lane = threadIdx.x & 63, wv = threadIdx.x >> 6;
    if (lane == 0) red[wv] = v;
    __syncthreads();
    if (threadIdx.x == 0) bsum[blockIdx.x] = red[0] + red[1] + red[2] + red[3];
}

__global__ void k_scan_base(const int* __restrict__ bsum, int* __restrict__ bbase,
                            int nb, int* __restrict__ row_off, int N) {
    if (threadIdx.x == 0 && blockIdx.x == 0) {
        int run = 0;
        for (int b = 0; b < nb; b++) { bbase[b] = run; run += bsum[b]; }
        row_off[N] = run;
    }
}

__global__ void k_scan_final(const int* __restrict__ counts, const int* __restrict__ bbase,
                             int* __restrict__ row_off, int n) {
    __shared__ int s[256];
    int tid = threadIdx.x;
    int i = blockIdx.x * 256 + tid;
    int v = (i < n) ? counts[i] : 0;
    s[tid] = v;
    __syncthreads();
    for (int off = 1; off < 256; off <<= 1) {
        int t = (tid >= off) ? s[tid - off] : 0;
        __syncthreads();
        s[tid] += t;
        __syncthreads();
    }
    if (i < n) row_off[i] = bbase[blockIdx.x] + s[tid] - v;  // exclusive
}

__global__ void k_scatter(const int* __restrict__ row, const int* __restrict__ col,
                          const float* __restrict__ val, const int* __restrict__ row_off,
                          int* __restrict__ fill, int* __restrict__ ccol,
                          float* __restrict__ cval, int E) {
    int i = blockIdx.x * blockDim.x + threadIdx.x;
    int stride = gridDim.x * blockDim.x;
    for (; i < E; i += stride) {
        int r = row[i];
        int pos = row_off[r] + atomicAdd(&fill[r], 1);
        ccol[pos] = col[i];
        cval[pos] = val[i];
    }
}

// ---------------- GEMM1: support(bf16) = x(f32) @ W1(f32) ----------------
// 64x64 tile, BK=16, 256 threads, 4x4 micro-tile per thread. f32 VALU.

__global__ __launch_bounds__(256) void k_gemm1(const float* __restrict__ A,
                                               const float* __restrict__ B,
                                               u16* __restrict__ Cb, int M) {
    __shared__ float As[16][68];  // transposed A tile, padded
    __shared__ float Bs[16][64];
    const int K = F_IN, N = HID;
    int tid = threadIdx.x;
    int bm = blockIdx.x * 64, bn = blockIdx.y * 64;
    int tx = tid & 15, ty = tid >> 4;

    int ar  = tid >> 2;         // 0..63 (A row in tile)
    int ac4 = (tid & 3) * 4;    // 0,4,8,12 (A col4 in tile)
    int br  = tid >> 4;         // 0..15 (B row in tile)
    int bc4 = (tid & 15) * 4;   // B col4 in tile

    float acc[4][4] = {};

    for (int k0 = 0; k0 < K; k0 += 16) {
        float4 av = make_float4(0.f, 0.f, 0.f, 0.f);
        int arow = bm + ar;
        if (arow < M)
            av = *reinterpret_cast<const float4*>(&A[(size_t)arow * K + k0 + ac4]);
        As[ac4 + 0][ar] = av.x;
        As[ac4 + 1][ar] = av.y;
        As[ac4 + 2][ar] = av.z;
        As[ac4 + 3][ar] = av.w;
        float4 bv = *reinterpret_cast<const float4*>(&B[(size_t)(k0 + br) * N + bn + bc4]);
        *reinterpret_cast<float4*>(&Bs[br][bc4]) = bv;
        __syncthreads();
#pragma unroll
        for (int k = 0; k < 16; k++) {
            float4 a = *reinterpret_cast<const float4*>(&As[k][ty * 4]);
            float4 b = *reinterpret_cast<const float4*>(&Bs[k][tx * 4]);
            float aa[4] = {a.x, a.y, a.z, a.w};
            float bb[4] = {b.x, b.y, b.z, b.w};
#pragma unroll
            for (int i = 0; i < 4; i++)
#pragma unroll
                for (int j = 0; j < 4; j++) acc[i][j] = fmaf(aa[i], bb[j], acc[i][j]);
        }
        __syncthreads();
    }
#pragma unroll
    for (int i = 0; i < 4; i++) {
        int r = bm + ty * 4 + i;
        if (r < M) {
#pragma unroll
            for (int j = 0; j < 4; j++)
                Cb[(size_t)r * N + bn + tx * 4 + j] = f2bf(acc[i][j]);
        }
    }
}

// ---------------- SPMM1 + bias + relu: h(bf16) = A @ support(bf16) ----------------
// One block (256 threads) per output row; thread = feature.

__global__ __launch_bounds__(256) void k_spmm1(const u16* __restrict__ Sb,
                                               const int* __restrict__ ccol,
                                               const float* __restrict__ cval,
                                               const int* __restrict__ row_off,
                                               const float* __restrict__ b1,
                                               u16* __restrict__ Hb) {
    int i = blockIdx.x;
    int tid = threadIdx.x;
    int beg = row_off[i], end = row_off[i + 1];
    float acc = 0.f;
    __shared__ int   scol[256];
    __shared__ float sval[256];
    for (int e0 = beg; e0 < end; e0 += 256) {
        int n = min(256, end - e0);
        __syncthreads();
        if (tid < n) { scol[tid] = ccol[e0 + tid]; sval[tid] = cval[e0 + tid]; }
        __syncthreads();
        for (int k = 0; k < n; k++)
            acc += sval[k] * bf2f(Sb[(size_t)scol[k] * HID + tid]);
    }
    float h = acc + b1[tid];
    Hb[(size_t)i * HID + tid] = f2bf(fmaxf(h, 0.f));
}

// ---------------- GEMM2: S2(f32) = h(bf16) @ W2(f32) ----------------
// Block handles 32 rows; h tile staged in LDS (f32); thread -> (row, 5 cols).

__global__ __launch_bounds__(256) void k_gemm2(const u16* __restrict__ Hb,
                                               const float* __restrict__ W2,
                                               float* __restrict__ S2) {
    __shared__ float hs[32][257];
    int tid = threadIdx.x;
    int base = blockIdx.x * 32;
#pragma unroll
    for (int rep = 0; rep < 32; rep++) {
        int idx = rep * 256 + tid;
        int r = idx >> 8, c = idx & 255;
        hs[r][c] = bf2f(Hb[(size_t)(base + r) * HID + c]);
    }
    __syncthreads();
    int r  = tid >> 3;        // 0..31
    int j0 = (tid & 7) * 5;   // 0..35
    float acc[5] = {0.f, 0.f, 0.f, 0.f, 0.f};
    for (int k = 0; k < HID; k++) {
        float hv = hs[r][k];
#pragma unroll
        for (int jj = 0; jj < 5; jj++)
            acc[jj] = fmaf(hv, W2[k * C_OUT + j0 + jj], acc[jj]);
    }
#pragma unroll
    for (int jj = 0; jj < 5; jj++)
        S2[(size_t)(base + r) * C_OUT + j0 + jj] = acc[jj];
}

// ---------------- SPMM2 + bias: logits = A @ S2 + b2 ----------------
// One wave per row; lanes 0..39 = classes.

__global__ __launch_bounds__(256) void k_spmm2(const float* __restrict__ S2,
                                               const int* __restrict__ ccol,
                                               const float* __restrict__ cval,
                                               const int* __restrict__ row_off,
                                               const float* __restrict__ b2,
                                               float* __restrict__ logits) {
    int wv = threadIdx.x >> 6;
    int lane = threadIdx.x & 63;
    int row = blockIdx.x * 4 + wv;
    int beg = row_off[row], end = row_off[row + 1];
    int l = (lane < C_OUT) ? lane : 0;
    float acc = 0.f;
    for (int e = beg; e < end; e++) {
        int c = ccol[e];
        float v = cval[e];
        acc = fmaf(v, S2[(size_t)c * C_OUT + l], acc);
    }
    if (lane < C_OUT) logits[(size_t)row * C_OUT + lane] = acc + b2[lane];
}

// ---------------- softmax / log_softmax ----------------

__global__ __launch_bounds__(256) void k_softmax(const float* __restrict__ logits,
                                                 float* __restrict__ out_ls,
                                                 float* __restrict__ out_sm) {
    int wv = threadIdx.x >> 6;
    int lane = threadIdx.x & 63;
    int row = blockIdx.x * 4 + wv;
    float v = (lane < C_OUT) ? logits[(size_t)row * C_OUT + lane] : -1e30f;
    float m = v;
    for (int s = 32; s; s >>= 1) m = fmaxf(m, __shfl_xor(m, s));
    float e = (lane < C_OUT) ? __expf(v - m) : 0.f;
    float sum = e;
    for (int s = 32; s; s >>= 1) sum += __shfl_xor(sum, s);
    float ls = v - m - __logf(sum);
    float sm = e / sum;
    if (lane < C_OUT) {
        out_ls[(size_t)row * C_OUT + lane] = ls;
        out_sm[(size_t)row * C_OUT + lane] = sm;
    }
}

// ---------------- launch ----------------

extern "C" void kernel_launch(void* const* d_in, const int* in_sizes, int n_in,
                              void* d_out, int out_size, void* d_ws, size_t ws_size,
                              hipStream_t stream) {
    const float* x    = (const float*)d_in[0];
    const float* W1   = (const float*)d_in[1];
    const float* b1   = (const float*)d_in[2];
    const float* W2   = (const float*)d_in[3];
    const float* b2   = (const float*)d_in[4];
    const int*   erow = (const int*)d_in[5];
    const int*   ecol = (const int*)d_in[6];
    const float* eval = (const float*)d_in[7];
    float* out = (float*)d_out;

    char* w = (char*)d_ws;
    auto alloc = [&](size_t bytes) {
        char* p = w;
        w += (bytes + 255) & ~(size_t)255;
        return p;
    };
    u16*   support = (u16*)  alloc((size_t)N_NODES * HID * sizeof(u16));
    u16*   hbuf    = (u16*)  alloc((size_t)N_NODES * HID * sizeof(u16));
    int*   ccol    = (int*)  alloc((size_t)N_EDGES * sizeof(int));
    float* cval    = (float*)alloc((size_t)N_EDGES * sizeof(float));
    int*   row_off = (int*)  alloc((size_t)(N_NODES + 1) * sizeof(int));
    int*   counts  = (int*)  alloc((size_t)N_NODES * sizeof(int));
    int*   fill    = (int*)  alloc((size_t)N_NODES * sizeof(int));
    int*   bsum    = (int*)  alloc(4096);
    int*   bbase   = (int*)  alloc(4096);
    float* S2      = (float*)alloc((size_t)N_NODES * C_OUT * sizeof(float));

    hipMemsetAsync(counts, 0, (size_t)N_NODES * sizeof(int), stream);
    hipMemsetAsync(fill,   0, (size_t)N_NODES * sizeof(int), stream);

    k_hist<<<1024, 256, 0, stream>>>(erow, counts, N_EDGES);
    int NB = (N_NODES + 255) / 256;  // 391
    k_scan_block<<<NB, 256, 0, stream>>>(counts, bsum, N_NODES);
    k_scan_base<<<1, 64, 0, stream>>>(bsum, bbase, NB, row_off, N_NODES);
    k_scan_final<<<NB, 256, 0, stream>>>(counts, bbase, row_off, N_NODES);
    k_scatter<<<1024, 256, 0, stream>>>(erow, ecol, eval, row_off, fill, ccol, cval, N_EDGES);

    dim3 g1((N_NODES + 63) / 64, HID / 64);
    k_gemm1<<<g1, 256, 0, stream>>>(x, W1, support, N_NODES);
    k_spmm1<<<N_NODES, 256, 0, stream>>>(support, ccol, cval, row_off, b1, hbuf);
    k_gemm2<<<N_NODES / 32, 256, 0, stream>>>(hbuf, W2, S2);
    k_spmm2<<<N_NODES / 4, 256, 0, stream>>>(S2, ccol, cval, row_off, b2, out);
    k_softmax<<<N_NODES / 4, 256, 0, stream>>>(out, out, out + (size_t)N_NODES * C_OUT);
}

// Round 2
// 981.097 us; speedup vs baseline: 1.5355x; 1.5355x over previous
//
#include <hip/hip_runtime.h>
#include <hip/hip_bf16.h>

#define N_NODES 100000
#define N_EDGES 3200000
#define F_IN    512
#define HID     256
#define C_OUT   40

typedef unsigned short u16;
typedef __attribute__((ext_vector_type(4))) unsigned short u16x4;
typedef __attribute__((ext_vector_type(8))) short bf16x8;
typedef __attribute__((ext_vector_type(4))) float f32x4;

__device__ __forceinline__ float bf2f(u16 u) {
    unsigned int x = ((unsigned int)u) << 16;
    return __uint_as_float(x);
}
__device__ __forceinline__ u16 f2bf(float f) {
    unsigned int x = __float_as_uint(f);
    return (u16)((x + 0x7fffu + ((x >> 16) & 1u)) >> 16);  // RNE
}
__device__ __forceinline__ unsigned int pk2(float lo, float hi) {
    return (unsigned int)f2bf(lo) | ((unsigned int)f2bf(hi) << 16);
}

// ---------------- CSR build ----------------

__global__ void k_hist(const int* __restrict__ row, int* __restrict__ counts, int E) {
    int i = blockIdx.x * blockDim.x + threadIdx.x;
    int stride = gridDim.x * blockDim.x;
    for (; i < E; i += stride) atomicAdd(&counts[row[i]], 1);
}

__global__ void k_scan_block(const int* __restrict__ counts, int* __restrict__ bsum, int n) {
    int i = blockIdx.x * 256 + threadIdx.x;
    int v = (i < n) ? counts[i] : 0;
    for (int s = 32; s; s >>= 1) v += __shfl_xor(v, s);
    __shared__ int red[4];
    int lane = threadIdx.x & 63, wv = threadIdx.x >> 6;
    if (lane == 0) red[wv] = v;
    __syncthreads();
    if (threadIdx.x == 0) bsum[blockIdx.x] = red[0] + red[1] + red[2] + red[3];
}

__global__ void k_scan_base(const int* __restrict__ bsum, int* __restrict__ bbase,
                            int nb, int* __restrict__ row_off, int N) {
    if (threadIdx.x == 0 && blockIdx.x == 0) {
        int run = 0;
        for (int b = 0; b < nb; b++) { bbase[b] = run; run += bsum[b]; }
        row_off[N] = run;
    }
}

__global__ void k_scan_final(const int* __restrict__ counts, const int* __restrict__ bbase,
                             int* __restrict__ row_off, int n) {
    __shared__ int s[256];
    int tid = threadIdx.x;
    int i = blockIdx.x * 256 + tid;
    int v = (i < n) ? counts[i] : 0;
    s[tid] = v;
    __syncthreads();
    for (int off = 1; off < 256; off <<= 1) {
        int t = (tid >= off) ? s[tid - off] : 0;
        __syncthreads();
        s[tid] += t;
        __syncthreads();
    }
    if (i < n) row_off[i] = bbase[blockIdx.x] + s[tid] - v;  // exclusive
}

__global__ void k_scatter(const int* __restrict__ row, const int* __restrict__ col,
                          const float* __restrict__ val, const int* __restrict__ row_off,
                          int* __restrict__ fill, int* __restrict__ ccol,
                          float* __restrict__ cval, int E) {
    int i = blockIdx.x * blockDim.x + threadIdx.x;
    int stride = gridDim.x * blockDim.x;
    for (; i < E; i += stride) {
        int r = row[i];
        int pos = row_off[r] + atomicAdd(&fill[r], 1);
        ccol[pos] = col[i];
        cval[pos] = val[i];
    }
}

// ---------------- W1 convert + transpose: W1t[n][k] bf16 ----------------

__global__ __launch_bounds__(256) void k_cvtW1(const float* __restrict__ W1,
                                               u16* __restrict__ W1t) {
    int i = blockIdx.x * 256 + threadIdx.x;  // over 512*256
    int k = i >> 8, n = i & 255;
    W1t[(size_t)n * F_IN + k] = f2bf(W1[i]);
}

// ---------------- GEMM1 (MFMA): support(bf16) = x(f32) @ W1(f32->bf16) ----------------
// 128x256 tile (BN=256 = full width -> A read exactly once), BK=32,
// 8 waves (2x4), wave computes 64x64 via 4x4 frags of 16x16x32 bf16 MFMA.
// LDS rows padded to 40 shorts (80B, 16B-aligned, 2-way bank aliasing = free).

#define ASTR 40
#define BSTR 40

__global__ __launch_bounds__(512) void k_gemm1(const float* __restrict__ A,
                                               const u16* __restrict__ Bt,  // [256][512] bf16
                                               u16* __restrict__ Cb, int M) {
    __shared__ u16 As[2][128 * ASTR];
    __shared__ u16 Bs[2][256 * BSTR];
    int tid = threadIdx.x;
    int bm = blockIdx.x * 128;
    int lane = tid & 63, wid = tid >> 6;
    int wm = wid >> 2, wn = wid & 3;

    // staging assignment
    int s_ar = tid >> 2;          // 0..127  (A row in tile)
    int s_ak = (tid & 3) * 8;     // 0,8,16,24 (k start, 8 f32 each)
    int s_bn = tid >> 1;          // 0..255  (B col = output col)
    int s_bk = (tid & 1) * 16;    // 0,16 (16 bf16 each)

    bool arow_ok = (bm + s_ar) < M;
    const float* aptr = A + (size_t)(bm + s_ar) * F_IN + s_ak;
    const u16*   bptr = Bt + (size_t)s_bn * F_IN + s_bk;

    f32x4 acc[4][4];
#pragma unroll
    for (int i = 0; i < 4; i++)
#pragma unroll
        for (int j = 0; j < 4; j++) acc[i][j] = (f32x4){0.f, 0.f, 0.f, 0.f};

    float4 ra0, ra1;
    int4 rb0, rb1;

    auto LOAD = [&](int kt) {
        const float* ap = aptr + kt * 32;
        if (arow_ok) {
            ra0 = *(const float4*)ap;
            ra1 = *(const float4*)(ap + 4);
        } else {
            ra0 = make_float4(0.f, 0.f, 0.f, 0.f);
            ra1 = ra0;
        }
        const u16* bp = bptr + kt * 32;
        rb0 = *(const int4*)bp;
        rb1 = *(const int4*)(bp + 8);
    };
    auto WRITE = [&](int buf) {
        int4 w;
        w.x = pk2(ra0.x, ra0.y);
        w.y = pk2(ra0.z, ra0.w);
        w.z = pk2(ra1.x, ra1.y);
        w.w = pk2(ra1.z, ra1.w);
        *(int4*)&As[buf][s_ar * ASTR + s_ak] = w;
        *(int4*)&Bs[buf][s_bn * BSTR + s_bk] = rb0;
        *(int4*)&Bs[buf][s_bn * BSTR + s_bk + 8] = rb1;
    };

    int kg = lane >> 4;    // k-group 0..3 (8 elems each)
    int r16 = lane & 15;

    auto COMPUTE = [&](int buf) {
        bf16x8 a[4], b[4];
#pragma unroll
        for (int mt = 0; mt < 4; mt++)
            a[mt] = *(const bf16x8*)&As[buf][(wm * 64 + mt * 16 + r16) * ASTR + kg * 8];
#pragma unroll
        for (int nt = 0; nt < 4; nt++)
            b[nt] = *(const bf16x8*)&Bs[buf][(wn * 64 + nt * 16 + r16) * BSTR + kg * 8];
#pragma unroll
        for (int mt = 0; mt < 4; mt++)
#pragma unroll
            for (int nt = 0; nt < 4; nt++)
                acc[mt][nt] = __builtin_amdgcn_mfma_f32_16x16x32_bf16(
                    a[mt], b[nt], acc[mt][nt], 0, 0, 0);
    };

    LOAD(0);
    WRITE(0);
    __syncthreads();
#pragma unroll 1
    for (int kt = 0; kt < F_IN / 32; kt++) {
        int cur = kt & 1;
        if (kt < F_IN / 32 - 1) LOAD(kt + 1);
        COMPUTE(cur);
        if (kt < F_IN / 32 - 1) WRITE(cur ^ 1);
        __syncthreads();
    }

    // C/D layout: col = lane&15, row = (lane>>4)*4 + j (m89-verified)
#pragma unroll
    for (int mt = 0; mt < 4; mt++) {
        int r0 = bm + wm * 64 + mt * 16 + (lane >> 4) * 4;
#pragma unroll
        for (int nt = 0; nt < 4; nt++) {
            int c = wn * 64 + nt * 16 + (lane & 15);
#pragma unroll
            for (int j = 0; j < 4; j++) {
                int r = r0 + j;
                if (r < M) Cb[(size_t)r * HID + c] = f2bf(acc[mt][nt][j]);
            }
        }
    }
}

// ---------------- SPMM1 + bias + relu: h(bf16) = A @ support(bf16) ----------------
// Wave per row; lane owns 4 features (8B gather per edge); edge col/val
// broadcast from a 64-edge register chunk via shfl; unroll 4 for MLP.

__global__ __launch_bounds__(256) void k_spmm1(const u16* __restrict__ Sb,
                                               const int* __restrict__ ccol,
                                               const float* __restrict__ cval,
                                               const int* __restrict__ row_off,
                                               const float* __restrict__ b1,
                                               u16* __restrict__ Hb) {
    int lane = threadIdx.x & 63;
    int row = blockIdx.x * 4 + (threadIdx.x >> 6);
    int beg = row_off[row], end = row_off[row + 1];
    float a0 = 0.f, a1 = 0.f, a2 = 0.f, a3 = 0.f;
    const u16* base = Sb + lane * 4;
    for (int e0 = beg; e0 < end; e0 += 64) {
        int m = min(64, end - e0);
        int idx = e0 + lane;
        int cc = (idx < end) ? ccol[idx] : 0;
        float vv = (idx < end) ? cval[idx] : 0.f;
        int k = 0;
        for (; k + 4 <= m; k += 4) {
            int c0 = __shfl(cc, k), c1 = __shfl(cc, k + 1);
            int c2 = __shfl(cc, k + 2), c3 = __shfl(cc, k + 3);
            float v0 = __shfl(vv, k), v1 = __shfl(vv, k + 1);
            float v2 = __shfl(vv, k + 2), v3 = __shfl(vv, k + 3);
            u16x4 s0 = *(const u16x4*)(base + (size_t)c0 * HID);
            u16x4 s1 = *(const u16x4*)(base + (size_t)c1 * HID);
            u16x4 s2 = *(const u16x4*)(base + (size_t)c2 * HID);
            u16x4 s3 = *(const u16x4*)(base + (size_t)c3 * HID);
            a0 += v0 * bf2f(s0.x) + v1 * bf2f(s1.x) + v2 * bf2f(s2.x) + v3 * bf2f(s3.x);
            a1 += v0 * bf2f(s0.y) + v1 * bf2f(s1.y) + v2 * bf2f(s2.y) + v3 * bf2f(s3.y);
            a2 += v0 * bf2f(s0.z) + v1 * bf2f(s1.z) + v2 * bf2f(s2.z) + v3 * bf2f(s3.z);
            a3 += v0 * bf2f(s0.w) + v1 * bf2f(s1.w) + v2 * bf2f(s2.w) + v3 * bf2f(s3.w);
        }
        for (; k < m; k++) {
            int c = __shfl(cc, k);
            float v = __shfl(vv, k);
            u16x4 s = *(const u16x4*)(base + (size_t)c * HID);
            a0 += v * bf2f(s.x);
            a1 += v * bf2f(s.y);
            a2 += v * bf2f(s.z);
            a3 += v * bf2f(s.w);
        }
    }
    float4 b = *(const float4*)&b1[lane * 4];
    u16x4 o;
    o.x = f2bf(fmaxf(a0 + b.x, 0.f));
    o.y = f2bf(fmaxf(a1 + b.y, 0.f));
    o.z = f2bf(fmaxf(a2 + b.z, 0.f));
    o.w = f2bf(fmaxf(a3 + b.w, 0.f));
    *(u16x4*)&Hb[(size_t)row * HID + lane * 4] = o;
}

// ---------------- GEMM2: S2(f32) = h(bf16) @ W2(f32) ----------------

__global__ __launch_bounds__(256) void k_gemm2(const u16* __restrict__ Hb,
                                               const float* __restrict__ W2,
                                               float* __restrict__ S2) {
    __shared__ float hs[32][257];
    int tid = threadIdx.x;
    int base = blockIdx.x * 32;
#pragma unroll
    for (int rep = 0; rep < 32; rep++) {
        int idx = rep * 256 + tid;
        int r = idx >> 8, c = idx & 255;
        hs[r][c] = bf2f(Hb[(size_t)(base + r) * HID + c]);
    }
    __syncthreads();
    int r  = tid >> 3;
    int j0 = (tid & 7) * 5;
    float acc[5] = {0.f, 0.f, 0.f, 0.f, 0.f};
    for (int k = 0; k < HID; k++) {
        float hv = hs[r][k];
#pragma unroll
        for (int jj = 0; jj < 5; jj++)
            acc[jj] = fmaf(hv, W2[k * C_OUT + j0 + jj], acc[jj]);
    }
#pragma unroll
    for (int jj = 0; jj < 5; jj++)
        S2[(size_t)(base + r) * C_OUT + j0 + jj] = acc[jj];
}

// ---------------- SPMM2 + bias + softmax/log_softmax (fused) ----------------
// Wave per row; lanes 0..39 = classes; shfl-chunked edges, unroll 4.

__global__ __launch_bounds__(256) void k_spmm2(const float* __restrict__ S2,
                                               const int* __restrict__ ccol,
                                               const float* __restrict__ cval,
                                               const int* __restrict__ row_off,
                                               const float* __restrict__ b2,
                                               float* __restrict__ out_ls,
                                               float* __restrict__ out_sm) {
    int lane = threadIdx.x & 63;
    int row = blockIdx.x * 4 + (threadIdx.x >> 6);
    int beg = row_off[row], end = row_off[row + 1];
    int l = (lane < C_OUT) ? lane : 0;
    float acc = 0.f;
    for (int e0 = beg; e0 < end; e0 += 64) {
        int m = min(64, end - e0);
        int idx = e0 + lane;
        int cc = (idx < end) ? ccol[idx] : 0;
        float vv = (idx < end) ? cval[idx] : 0.f;
        int k = 0;
        for (; k + 4 <= m; k += 4) {
            int c0 = __shfl(cc, k), c1 = __shfl(cc, k + 1);
            int c2 = __shfl(cc, k + 2), c3 = __shfl(cc, k + 3);
            float v0 = __shfl(vv, k), v1 = __shfl(vv, k + 1);
            float v2 = __shfl(vv, k + 2), v3 = __shfl(vv, k + 3);
            float s0 = S2[(size_t)c0 * C_OUT + l];
            float s1 = S2[(size_t)c1 * C_OUT + l];
            float s2 = S2[(size_t)c2 * C_OUT + l];
            float s3 = S2[(size_t)c3 * C_OUT + l];
            acc += v0 * s0 + v1 * s1 + v2 * s2 + v3 * s3;
        }
        for (; k < m; k++) {
            int c = __shfl(cc, k);
            float v = __shfl(vv, k);
            acc = fmaf(v, S2[(size_t)c * C_OUT + l], acc);
        }
    }
    float v = (lane < C_OUT) ? (acc + b2[l]) : -1e30f;
    float mx = v;
    for (int s = 32; s; s >>= 1) mx = fmaxf(mx, __shfl_xor(mx, s));
    float e = (lane < C_OUT) ? __expf(v - mx) : 0.f;
    float sum = e;
    for (int s = 32; s; s >>= 1) sum += __shfl_xor(sum, s);
    float ls = v - mx - __logf(sum);
    float sm = e / sum;
    if (lane < C_OUT) {
        out_ls[(size_t)row * C_OUT + lane] = ls;
        out_sm[(size_t)row * C_OUT + lane] = sm;
    }
}

// ---------------- launch ----------------

extern "C" void kernel_launch(void* const* d_in, const int* in_sizes, int n_in,
                              void* d_out, int out_size, void* d_ws, size_t ws_size,
                              hipStream_t stream) {
    const float* x    = (const float*)d_in[0];
    const float* W1   = (const float*)d_in[1];
    const float* b1   = (const float*)d_in[2];
    const float* W2   = (const float*)d_in[3];
    const float* b2   = (const float*)d_in[4];
    const int*   erow = (const int*)d_in[5];
    const int*   ecol = (const int*)d_in[6];
    const float* eval = (const float*)d_in[7];
    float* out = (float*)d_out;

    char* w = (char*)d_ws;
    auto alloc = [&](size_t bytes) {
        char* p = w;
        w += (bytes + 255) & ~(size_t)255;
        return p;
    };
    u16*   support = (u16*)  alloc((size_t)N_NODES * HID * sizeof(u16));
    u16*   hbuf    = (u16*)  alloc((size_t)N_NODES * HID * sizeof(u16));
    int*   ccol    = (int*)  alloc((size_t)N_EDGES * sizeof(int));
    float* cval    = (float*)alloc((size_t)N_EDGES * sizeof(float));
    int*   row_off = (int*)  alloc((size_t)(N_NODES + 1) * sizeof(int));
    int*   counts  = (int*)  alloc((size_t)N_NODES * sizeof(int));
    int*   fill    = (int*)  alloc((size_t)N_NODES * sizeof(int));
    int*   bsum    = (int*)  alloc(4096);
    int*   bbase   = (int*)  alloc(4096);
    float* S2      = (float*)alloc((size_t)N_NODES * C_OUT * sizeof(float));
    // W1t (256KB) aliases S2's buffer: needed only during gemm1, S2 written later.
    u16*   W1t     = (u16*)S2;

    hipMemsetAsync(counts, 0, (size_t)N_NODES * sizeof(int), stream);
    hipMemsetAsync(fill,   0, (size_t)N_NODES * sizeof(int), stream);

    k_hist<<<1024, 256, 0, stream>>>(erow, counts, N_EDGES);
    int NB = (N_NODES + 255) / 256;  // 391
    k_scan_block<<<NB, 256, 0, stream>>>(counts, bsum, N_NODES);
    k_scan_base<<<1, 64, 0, stream>>>(bsum, bbase, NB, row_off, N_NODES);
    k_scan_final<<<NB, 256, 0, stream>>>(counts, bbase, row_off, N_NODES);
    k_scatter<<<1024, 256, 0, stream>>>(erow, ecol, eval, row_off, fill, ccol, cval, N_EDGES);

    k_cvtW1<<<(F_IN * HID) / 256, 256, 0, stream>>>(W1, W1t);
    k_gemm1<<<(N_NODES + 127) / 128, 512, 0, stream>>>(x, W1t, support, N_NODES);
    k_spmm1<<<N_NODES / 4, 256, 0, stream>>>(support, ccol, cval, row_off, b1, hbuf);
    k_gemm2<<<N_NODES / 32, 256, 0, stream>>>(hbuf, W2, S2);
    k_spmm2<<<N_NODES / 4, 256, 0, stream>>>(S2, ccol, cval, row_off, b2,
                                             out, out + (size_t)N_NODES * C_OUT);
}

// Round 3
// 906.970 us; speedup vs baseline: 1.6610x; 1.0817x over previous
//
#include <hip/hip_runtime.h>
#include <hip/hip_bf16.h>

#define N_NODES 100000
#define N_EDGES 3200000
#define F_IN    512
#define HID     256
#define C_OUT   40

typedef unsigned short u16;
typedef __attribute__((ext_vector_type(4))) unsigned short u16x4;
typedef __attribute__((ext_vector_type(8))) short bf16x8;
typedef __attribute__((ext_vector_type(4))) float f32x4;

__device__ __forceinline__ float bf2f(u16 u) {
    unsigned int x = ((unsigned int)u) << 16;
    return __uint_as_float(x);
}
__device__ __forceinline__ u16 f2bf(float f) {
    unsigned int x = __float_as_uint(f);
    return (u16)((x + 0x7fffu + ((x >> 16) & 1u)) >> 16);  // RNE
}
__device__ __forceinline__ unsigned int pk2(float lo, float hi) {
    return (unsigned int)f2bf(lo) | ((unsigned int)f2bf(hi) << 16);
}

// ---------------- CSR build ----------------

__global__ __launch_bounds__(256) void k_hist(const int* __restrict__ row,
                                              int* __restrict__ counts) {
    int i = blockIdx.x * 256 + threadIdx.x;
    if (i < N_EDGES) atomicAdd(&counts[row[i]], 1);
}

__global__ void k_scan_block(const int* __restrict__ counts, int* __restrict__ bsum, int n) {
    int i = blockIdx.x * 256 + threadIdx.x;
    int v = (i < n) ? counts[i] : 0;
    for (int s = 32; s; s >>= 1) v += __shfl_xor(v, s);
    __shared__ int red[4];
    int lane = threadIdx.x & 63, wv = threadIdx.x >> 6;
    if (lane == 0) red[wv] = v;
    __syncthreads();
    if (threadIdx.x == 0) bsum[blockIdx.x] = red[0] + red[1] + red[2] + red[3];
}

__global__ void k_scan_base(const int* __restrict__ bsum, int* __restrict__ bbase,
                            int nb, int* __restrict__ row_off, int N) {
    if (threadIdx.x == 0 && blockIdx.x == 0) {
        int run = 0;
        for (int b = 0; b < nb; b++) { bbase[b] = run; run += bsum[b]; }
        row_off[N] = run;
    }
}

__global__ void k_scan_final(const int* __restrict__ counts, const int* __restrict__ bbase,
                             int* __restrict__ row_off, int n) {
    __shared__ int s[256];
    int tid = threadIdx.x;
    int i = blockIdx.x * 256 + tid;
    int v = (i < n) ? counts[i] : 0;
    s[tid] = v;
    __syncthreads();
    for (int off = 1; off < 256; off <<= 1) {
        int t = (tid >= off) ? s[tid - off] : 0;
        __syncthreads();
        s[tid] += t;
        __syncthreads();
    }
    if (i < n) row_off[i] = bbase[blockIdx.x] + s[tid] - v;  // exclusive
}

// Packed scatter: one 8B store per edge, one edge per thread.
__global__ __launch_bounds__(256) void k_scatter(const int* __restrict__ row,
                                                 const int* __restrict__ col,
                                                 const float* __restrict__ val,
                                                 const int* __restrict__ row_off,
                                                 int* __restrict__ fill,
                                                 int2* __restrict__ cpack) {
    int i = blockIdx.x * 256 + threadIdx.x;
    if (i >= N_EDGES) return;
    int r = row[i];
    int c = col[i];
    float v = val[i];
    int pos = row_off[r] + atomicAdd(&fill[r], 1);
    cpack[pos] = make_int2(c, __float_as_int(v));
}

// ---------------- W1 convert + transpose: W1t[n][k] bf16 ----------------

__global__ __launch_bounds__(256) void k_cvtW1(const float* __restrict__ W1,
                                               u16* __restrict__ W1t) {
    int i = blockIdx.x * 256 + threadIdx.x;  // over 512*256
    int k = i >> 8, n = i & 255;
    W1t[(size_t)n * F_IN + k] = f2bf(W1[i]);
}

// ---------------- GEMM1 (MFMA): support(bf16) = x(f32) @ W1(f32->bf16) ----------------
// 128x256 tile (BN=256 = full width -> A read exactly once), BK=32,
// 8 waves (2x4), wave computes 64x64 via 4x4 frags of 16x16x32 bf16 MFMA.

#define ASTR 40
#define BSTR 40

__global__ __launch_bounds__(512) void k_gemm1(const float* __restrict__ A,
                                               const u16* __restrict__ Bt,  // [256][512] bf16
                                               u16* __restrict__ Cb, int M) {
    __shared__ u16 As[2][128 * ASTR];
    __shared__ u16 Bs[2][256 * BSTR];
    int tid = threadIdx.x;
    int bm = blockIdx.x * 128;
    int lane = tid & 63, wid = tid >> 6;
    int wm = wid >> 2, wn = wid & 3;

    int s_ar = tid >> 2;          // 0..127
    int s_ak = (tid & 3) * 8;     // 0,8,16,24
    int s_bn = tid >> 1;          // 0..255
    int s_bk = (tid & 1) * 16;    // 0,16

    bool arow_ok = (bm + s_ar) < M;
    const float* aptr = A + (size_t)(bm + s_ar) * F_IN + s_ak;
    const u16*   bptr = Bt + (size_t)s_bn * F_IN + s_bk;

    f32x4 acc[4][4];
#pragma unroll
    for (int i = 0; i < 4; i++)
#pragma unroll
        for (int j = 0; j < 4; j++) acc[i][j] = (f32x4){0.f, 0.f, 0.f, 0.f};

    float4 ra0, ra1;
    int4 rb0, rb1;

    auto LOAD = [&](int kt) {
        const float* ap = aptr + kt * 32;
        if (arow_ok) {
            ra0 = *(const float4*)ap;
            ra1 = *(const float4*)(ap + 4);
        } else {
            ra0 = make_float4(0.f, 0.f, 0.f, 0.f);
            ra1 = ra0;
        }
        const u16* bp = bptr + kt * 32;
        rb0 = *(const int4*)bp;
        rb1 = *(const int4*)(bp + 8);
    };
    auto WRITE = [&](int buf) {
        int4 w;
        w.x = pk2(ra0.x, ra0.y);
        w.y = pk2(ra0.z, ra0.w);
        w.z = pk2(ra1.x, ra1.y);
        w.w = pk2(ra1.z, ra1.w);
        *(int4*)&As[buf][s_ar * ASTR + s_ak] = w;
        *(int4*)&Bs[buf][s_bn * BSTR + s_bk] = rb0;
        *(int4*)&Bs[buf][s_bn * BSTR + s_bk + 8] = rb1;
    };

    int kg = lane >> 4;
    int r16 = lane & 15;

    auto COMPUTE = [&](int buf) {
        bf16x8 a[4], b[4];
#pragma unroll
        for (int mt = 0; mt < 4; mt++)
            a[mt] = *(const bf16x8*)&As[buf][(wm * 64 + mt * 16 + r16) * ASTR + kg * 8];
#pragma unroll
        for (int nt = 0; nt < 4; nt++)
            b[nt] = *(const bf16x8*)&Bs[buf][(wn * 64 + nt * 16 + r16) * BSTR + kg * 8];
#pragma unroll
        for (int mt = 0; mt < 4; mt++)
#pragma unroll
            for (int nt = 0; nt < 4; nt++)
                acc[mt][nt] = __builtin_amdgcn_mfma_f32_16x16x32_bf16(
                    a[mt], b[nt], acc[mt][nt], 0, 0, 0);
    };

    LOAD(0);
    WRITE(0);
    __syncthreads();
#pragma unroll 1
    for (int kt = 0; kt < F_IN / 32; kt++) {
        int cur = kt & 1;
        if (kt < F_IN / 32 - 1) LOAD(kt + 1);
        COMPUTE(cur);
        if (kt < F_IN / 32 - 1) WRITE(cur ^ 1);
        __syncthreads();
    }

#pragma unroll
    for (int mt = 0; mt < 4; mt++) {
        int r0 = bm + wm * 64 + mt * 16 + (lane >> 4) * 4;
#pragma unroll
        for (int nt = 0; nt < 4; nt++) {
            int c = wn * 64 + nt * 16 + (lane & 15);
#pragma unroll
            for (int j = 0; j < 4; j++) {
                int r = r0 + j;
                if (r < M) Cb[(size_t)r * HID + c] = f2bf(acc[mt][nt][j]);
            }
        }
    }
}

// ---------------- SPMM1 + bias + relu: h(bf16) = A @ support(bf16) ----------------
// Wave per row; lane owns 4 features (8B gather/edge); packed edge stream.

__global__ __launch_bounds__(256) void k_spmm1(const u16* __restrict__ Sb,
                                               const int2* __restrict__ cpack,
                                               const int* __restrict__ row_off,
                                               const float* __restrict__ b1,
                                               u16* __restrict__ Hb) {
    int lane = threadIdx.x & 63;
    int row = blockIdx.x * 4 + (threadIdx.x >> 6);
    int beg = row_off[row], end = row_off[row + 1];
    float a0 = 0.f, a1 = 0.f, a2 = 0.f, a3 = 0.f;
    const u16* base = Sb + lane * 4;
    for (int e0 = beg; e0 < end; e0 += 64) {
        int m = min(64, end - e0);
        int idx = e0 + lane;
        int2 p = (idx < end) ? cpack[idx] : make_int2(0, 0);
        int cc = p.x;
        float vv = __int_as_float(p.y);
        int k = 0;
        for (; k + 4 <= m; k += 4) {
            int c0 = __shfl(cc, k), c1 = __shfl(cc, k + 1);
            int c2 = __shfl(cc, k + 2), c3 = __shfl(cc, k + 3);
            float v0 = __shfl(vv, k), v1 = __shfl(vv, k + 1);
            float v2 = __shfl(vv, k + 2), v3 = __shfl(vv, k + 3);
            u16x4 s0 = *(const u16x4*)(base + (size_t)c0 * HID);
            u16x4 s1 = *(const u16x4*)(base + (size_t)c1 * HID);
            u16x4 s2 = *(const u16x4*)(base + (size_t)c2 * HID);
            u16x4 s3 = *(const u16x4*)(base + (size_t)c3 * HID);
            a0 += v0 * bf2f(s0.x) + v1 * bf2f(s1.x) + v2 * bf2f(s2.x) + v3 * bf2f(s3.x);
            a1 += v0 * bf2f(s0.y) + v1 * bf2f(s1.y) + v2 * bf2f(s2.y) + v3 * bf2f(s3.y);
            a2 += v0 * bf2f(s0.z) + v1 * bf2f(s1.z) + v2 * bf2f(s2.z) + v3 * bf2f(s3.z);
            a3 += v0 * bf2f(s0.w) + v1 * bf2f(s1.w) + v2 * bf2f(s2.w) + v3 * bf2f(s3.w);
        }
        for (; k < m; k++) {
            int c = __shfl(cc, k);
            float v = __shfl(vv, k);
            u16x4 s = *(const u16x4*)(base + (size_t)c * HID);
            a0 += v * bf2f(s.x);
            a1 += v * bf2f(s.y);
            a2 += v * bf2f(s.z);
            a3 += v * bf2f(s.w);
        }
    }
    float4 b = *(const float4*)&b1[lane * 4];
    u16x4 o;
    o.x = f2bf(fmaxf(a0 + b.x, 0.f));
    o.y = f2bf(fmaxf(a1 + b.y, 0.f));
    o.z = f2bf(fmaxf(a2 + b.z, 0.f));
    o.w = f2bf(fmaxf(a3 + b.w, 0.f));
    *(u16x4*)&Hb[(size_t)row * HID + lane * 4] = o;
}

// ---------------- GEMM2: S2(bf16) = h(bf16) @ W2(f32) ----------------

__global__ __launch_bounds__(256) void k_gemm2(const u16* __restrict__ Hb,
                                               const float* __restrict__ W2,
                                               u16* __restrict__ S2b) {
    __shared__ float hs[32][257];
    int tid = threadIdx.x;
    int base = blockIdx.x * 32;
#pragma unroll
    for (int rep = 0; rep < 32; rep++) {
        int idx = rep * 256 + tid;
        int r = idx >> 8, c = idx & 255;
        hs[r][c] = bf2f(Hb[(size_t)(base + r) * HID + c]);
    }
    __syncthreads();
    int r  = tid >> 3;
    int j0 = (tid & 7) * 5;
    float acc[5] = {0.f, 0.f, 0.f, 0.f, 0.f};
    for (int k = 0; k < HID; k++) {
        float hv = hs[r][k];
#pragma unroll
        for (int jj = 0; jj < 5; jj++)
            acc[jj] = fmaf(hv, W2[k * C_OUT + j0 + jj], acc[jj]);
    }
#pragma unroll
    for (int jj = 0; jj < 5; jj++)
        S2b[(size_t)(base + r) * C_OUT + j0 + jj] = f2bf(acc[jj]);
}

// ---------------- SPMM2 + bias + softmax/log_softmax (fused) ----------------
// Wave per row; lanes 0..39 = classes; bf16 S2 gather; packed edge stream.

__global__ __launch_bounds__(256) void k_spmm2(const u16* __restrict__ S2b,
                                               const int2* __restrict__ cpack,
                                               const int* __restrict__ row_off,
                                               const float* __restrict__ b2,
                                               float* __restrict__ out_ls,
                                               float* __restrict__ out_sm) {
    int lane = threadIdx.x & 63;
    int row = blockIdx.x * 4 + (threadIdx.x >> 6);
    int beg = row_off[row], end = row_off[row + 1];
    int l = (lane < C_OUT) ? lane : 0;
    float acc = 0.f;
    for (int e0 = beg; e0 < end; e0 += 64) {
        int m = min(64, end - e0);
        int idx = e0 + lane;
        int2 p = (idx < end) ? cpack[idx] : make_int2(0, 0);
        int cc = p.x;
        float vv = __int_as_float(p.y);
        int k = 0;
        for (; k + 4 <= m; k += 4) {
            int c0 = __shfl(cc, k), c1 = __shfl(cc, k + 1);
            int c2 = __shfl(cc, k + 2), c3 = __shfl(cc, k + 3);
            float v0 = __shfl(vv, k), v1 = __shfl(vv, k + 1);
            float v2 = __shfl(vv, k + 2), v3 = __shfl(vv, k + 3);
            float s0 = bf2f(S2b[(size_t)c0 * C_OUT + l]);
            float s1 = bf2f(S2b[(size_t)c1 * C_OUT + l]);
            float s2 = bf2f(S2b[(size_t)c2 * C_OUT + l]);
            float s3 = bf2f(S2b[(size_t)c3 * C_OUT + l]);
            acc += v0 * s0 + v1 * s1 + v2 * s2 + v3 * s3;
        }
        for (; k < m; k++) {
            int c = __shfl(cc, k);
            float v = __shfl(vv, k);
            acc = fmaf(v, bf2f(S2b[(size_t)c * C_OUT + l]), acc);
        }
    }
    float v = (lane < C_OUT) ? (acc + b2[l]) : -1e30f;
    float mx = v;
    for (int s = 32; s; s >>= 1) mx = fmaxf(mx, __shfl_xor(mx, s));
    float e = (lane < C_OUT) ? __expf(v - mx) : 0.f;
    float sum = e;
    for (int s = 32; s; s >>= 1) sum += __shfl_xor(sum, s);
    float ls = v - mx - __logf(sum);
    float sm = e / sum;
    if (lane < C_OUT) {
        out_ls[(size_t)row * C_OUT + lane] = ls;
        out_sm[(size_t)row * C_OUT + lane] = sm;
    }
}

// ---------------- launch ----------------

extern "C" void kernel_launch(void* const* d_in, const int* in_sizes, int n_in,
                              void* d_out, int out_size, void* d_ws, size_t ws_size,
                              hipStream_t stream) {
    const float* x    = (const float*)d_in[0];
    const float* W1   = (const float*)d_in[1];
    const float* b1   = (const float*)d_in[2];
    const float* W2   = (const float*)d_in[3];
    const float* b2   = (const float*)d_in[4];
    const int*   erow = (const int*)d_in[5];
    const int*   ecol = (const int*)d_in[6];
    const float* eval = (const float*)d_in[7];
    float* out = (float*)d_out;

    char* w = (char*)d_ws;
    auto alloc = [&](size_t bytes) {
        char* p = w;
        w += (bytes + 255) & ~(size_t)255;
        return p;
    };
    u16*   support = (u16*)  alloc((size_t)N_NODES * HID * sizeof(u16));
    u16*   hbuf    = (u16*)  alloc((size_t)N_NODES * HID * sizeof(u16));
    int2*  cpack   = (int2*) alloc((size_t)N_EDGES * sizeof(int2));
    int*   row_off = (int*)  alloc((size_t)(N_NODES + 1) * sizeof(int));
    int*   counts  = (int*)  alloc((size_t)N_NODES * sizeof(int));
    int*   fill    = (int*)  alloc((size_t)N_NODES * sizeof(int));
    int*   bsum    = (int*)  alloc(4096);
    int*   bbase   = (int*)  alloc(4096);
    u16*   S2b     = (u16*)  alloc((size_t)N_NODES * C_OUT * sizeof(u16));
    // W1t (256KB) aliases S2b's buffer: needed only during gemm1, S2b written later.
    u16*   W1t     = (u16*)S2b;

    hipMemsetAsync(counts, 0, (size_t)N_NODES * sizeof(int), stream);
    hipMemsetAsync(fill,   0, (size_t)N_NODES * sizeof(int), stream);

    int EB = (N_EDGES + 255) / 256;  // 12500
    k_hist<<<EB, 256, 0, stream>>>(erow, counts);
    int NB = (N_NODES + 255) / 256;  // 391
    k_scan_block<<<NB, 256, 0, stream>>>(counts, bsum, N_NODES);
    k_scan_base<<<1, 64, 0, stream>>>(bsum, bbase, NB, row_off, N_NODES);
    k_scan_final<<<NB, 256, 0, stream>>>(counts, bbase, row_off, N_NODES);
    k_scatter<<<EB, 256, 0, stream>>>(erow, ecol, eval, row_off, fill, cpack);

    k_cvtW1<<<(F_IN * HID) / 256, 256, 0, stream>>>(W1, W1t);
    k_gemm1<<<(N_NODES + 127) / 128, 512, 0, stream>>>(x, W1t, support, N_NODES);
    k_spmm1<<<N_NODES / 4, 256, 0, stream>>>(support, cpack, row_off, b1, hbuf);
    k_gemm2<<<N_NODES / 32, 256, 0, stream>>>(hbuf, W2, S2b);
    k_spmm2<<<N_NODES / 4, 256, 0, stream>>>(S2b, cpack, row_off, b2,
                                             out, out + (size_t)N_NODES * C_OUT);
}

// Round 5
// 736.876 us; speedup vs baseline: 2.0444x; 1.2308x over previous
//
#include <hip/hip_runtime.h>
#include <hip/hip_bf16.h>

#define N_NODES 100000
#define N_EDGES 3200000
#define F_IN    512
#define HID     256
#define C_OUT   40

typedef unsigned short u16;
typedef __attribute__((ext_vector_type(4))) unsigned short u16x4;
typedef __attribute__((ext_vector_type(8))) unsigned short u16x8;
typedef __attribute__((ext_vector_type(8))) short bf16x8;
typedef __attribute__((ext_vector_type(4))) float f32x4;

__device__ __forceinline__ float bf2f(u16 u) {
    unsigned int x = ((unsigned int)u) << 16;
    return __uint_as_float(x);
}
__device__ __forceinline__ u16 f2bf(float f) {
    unsigned int x = __float_as_uint(f);
    return (u16)((x + 0x7fffu + ((x >> 16) & 1u)) >> 16);  // RNE
}
__device__ __forceinline__ unsigned int pk2(float lo, float hi) {
    return (unsigned int)f2bf(lo) | ((unsigned int)f2bf(hi) << 16);
}

// ---------------- CSR build ----------------

__global__ __launch_bounds__(256) void k_hist(const int* __restrict__ row,
                                              int* __restrict__ counts) {
    int i = blockIdx.x * 256 + threadIdx.x;
    if (i < N_EDGES) atomicAdd(&counts[row[i]], 1);
}

__global__ void k_scan_block(const int* __restrict__ counts, int* __restrict__ bsum, int n) {
    int i = blockIdx.x * 256 + threadIdx.x;
    int v = (i < n) ? counts[i] : 0;
    for (int s = 32; s; s >>= 1) v += __shfl_xor(v, s);
    __shared__ int red[4];
    int lane = threadIdx.x & 63, wv = threadIdx.x >> 6;
    if (lane == 0) red[wv] = v;
    __syncthreads();
    if (threadIdx.x == 0) bsum[blockIdx.x] = red[0] + red[1] + red[2] + red[3];
}

__global__ void k_scan_base(const int* __restrict__ bsum, int* __restrict__ bbase,
                            int nb, int* __restrict__ row_off, int N) {
    if (threadIdx.x == 0 && blockIdx.x == 0) {
        int run = 0;
        for (int b = 0; b < nb; b++) { bbase[b] = run; run += bsum[b]; }
        row_off[N] = run;
    }
}

__global__ void k_scan_final(const int* __restrict__ counts, const int* __restrict__ bbase,
                             int* __restrict__ row_off, int n) {
    __shared__ int s[256];
    int tid = threadIdx.x;
    int i = blockIdx.x * 256 + tid;
    int v = (i < n) ? counts[i] : 0;
    s[tid] = v;
    __syncthreads();
    for (int off = 1; off < 256; off <<= 1) {
        int t = (tid >= off) ? s[tid - off] : 0;
        __syncthreads();
        s[tid] += t;
        __syncthreads();
    }
    if (i < n) row_off[i] = bbase[blockIdx.x] + s[tid] - v;  // exclusive
}

// Packed scatter: one 8B store per edge, one edge per thread.
__global__ __launch_bounds__(256) void k_scatter(const int* __restrict__ row,
                                                 const int* __restrict__ col,
                                                 const float* __restrict__ val,
                                                 const int* __restrict__ row_off,
                                                 int* __restrict__ fill,
                                                 int2* __restrict__ cpack) {
    int i = blockIdx.x * 256 + threadIdx.x;
    if (i >= N_EDGES) return;
    int r = row[i];
    int c = col[i];
    float v = val[i];
    int pos = row_off[r] + atomicAdd(&fill[r], 1);
    cpack[pos] = make_int2(c, __float_as_int(v));
}

// ---------------- weight converts ----------------

__global__ __launch_bounds__(256) void k_cvtW1(const float* __restrict__ W1,
                                               u16* __restrict__ W1t) {
    int i = blockIdx.x * 256 + threadIdx.x;  // over 512*256
    int k = i >> 8, n = i & 255;
    W1t[(size_t)n * F_IN + k] = f2bf(W1[i]);
}

// W2t: [64][256] bf16, classes 40..63 zero-padded.
__global__ __launch_bounds__(256) void k_cvtW2(const float* __restrict__ W2,
                                               u16* __restrict__ W2t) {
    int i = blockIdx.x * 256 + threadIdx.x;  // over 64*256
    int n = i >> 8, k = i & 255;
    W2t[i] = (n < C_OUT) ? f2bf(W2[k * C_OUT + n]) : (u16)0;
}

// ---------------- GEMM1 (MFMA): support(bf16) = x(f32) @ W1t ----------------

#define ASTR 40
#define BSTR 40

__global__ __launch_bounds__(512) void k_gemm1(const float* __restrict__ A,
                                               const u16* __restrict__ Bt,  // [256][512] bf16
                                               u16* __restrict__ Cb, int M) {
    __shared__ u16 As[2][128 * ASTR];
    __shared__ u16 Bs[2][256 * BSTR];
    int tid = threadIdx.x;
    int bm = blockIdx.x * 128;
    int lane = tid & 63, wid = tid >> 6;
    int wm = wid >> 2, wn = wid & 3;

    int s_ar = tid >> 2;
    int s_ak = (tid & 3) * 8;
    int s_bn = tid >> 1;
    int s_bk = (tid & 1) * 16;

    bool arow_ok = (bm + s_ar) < M;
    const float* aptr = A + (size_t)(bm + s_ar) * F_IN + s_ak;
    const u16*   bptr = Bt + (size_t)s_bn * F_IN + s_bk;

    f32x4 acc[4][4];
#pragma unroll
    for (int i = 0; i < 4; i++)
#pragma unroll
        for (int j = 0; j < 4; j++) acc[i][j] = (f32x4){0.f, 0.f, 0.f, 0.f};

    float4 ra0, ra1;
    int4 rb0, rb1;

    auto LOAD = [&](int kt) {
        const float* ap = aptr + kt * 32;
        if (arow_ok) {
            ra0 = *(const float4*)ap;
            ra1 = *(const float4*)(ap + 4);
        } else {
            ra0 = make_float4(0.f, 0.f, 0.f, 0.f);
            ra1 = ra0;
        }
        const u16* bp = bptr + kt * 32;
        rb0 = *(const int4*)bp;
        rb1 = *(const int4*)(bp + 8);
    };
    auto WRITE = [&](int buf) {
        int4 w;
        w.x = pk2(ra0.x, ra0.y);
        w.y = pk2(ra0.z, ra0.w);
        w.z = pk2(ra1.x, ra1.y);
        w.w = pk2(ra1.z, ra1.w);
        *(int4*)&As[buf][s_ar * ASTR + s_ak] = w;
        *(int4*)&Bs[buf][s_bn * BSTR + s_bk] = rb0;
        *(int4*)&Bs[buf][s_bn * BSTR + s_bk + 8] = rb1;
    };

    int kg = lane >> 4;
    int r16 = lane & 15;

    auto COMPUTE = [&](int buf) {
        bf16x8 a[4], b[4];
#pragma unroll
        for (int mt = 0; mt < 4; mt++)
            a[mt] = *(const bf16x8*)&As[buf][(wm * 64 + mt * 16 + r16) * ASTR + kg * 8];
#pragma unroll
        for (int nt = 0; nt < 4; nt++)
            b[nt] = *(const bf16x8*)&Bs[buf][(wn * 64 + nt * 16 + r16) * BSTR + kg * 8];
#pragma unroll
        for (int mt = 0; mt < 4; mt++)
#pragma unroll
            for (int nt = 0; nt < 4; nt++)
                acc[mt][nt] = __builtin_amdgcn_mfma_f32_16x16x32_bf16(
                    a[mt], b[nt], acc[mt][nt], 0, 0, 0);
    };

    LOAD(0);
    WRITE(0);
    __syncthreads();
#pragma unroll 1
    for (int kt = 0; kt < F_IN / 32; kt++) {
        int cur = kt & 1;
        if (kt < F_IN / 32 - 1) LOAD(kt + 1);
        COMPUTE(cur);
        if (kt < F_IN / 32 - 1) WRITE(cur ^ 1);
        __syncthreads();
    }

#pragma unroll
    for (int mt = 0; mt < 4; mt++) {
        int r0 = bm + wm * 64 + mt * 16 + (lane >> 4) * 4;
#pragma unroll
        for (int nt = 0; nt < 4; nt++) {
            int c = wn * 64 + nt * 16 + (lane & 15);
#pragma unroll
            for (int j = 0; j < 4; j++) {
                int r = r0 + j;
                if (r < M) Cb[(size_t)r * HID + c] = f2bf(acc[mt][nt][j]);
            }
        }
    }
}

// ---------------- SPMM1 + bias + relu: h(bf16) = A @ support(bf16) ----------------
// Wave per row; 2 edges per step: half = lane>>5 picks the edge, lane owns
// 8 features via one dwordx4 gather. Cross-half shfl_xor(32) reduce at end.

__global__ __launch_bounds__(256) void k_spmm1(const u16* __restrict__ Sb,
                                               const int2* __restrict__ cpack,
                                               const int* __restrict__ row_off,
                                               const float* __restrict__ b1,
                                               u16* __restrict__ Hb) {
    int lane = threadIdx.x & 63;
    int row = blockIdx.x * 4 + (threadIdx.x >> 6);
    int beg = row_off[row], end = row_off[row + 1];
    int half = lane >> 5;
    int f8 = (lane & 31) * 8;
    const u16* base = Sb + f8;
    float acc[8] = {};
    for (int e0 = beg; e0 < end; e0 += 64) {
        int m = min(64, end - e0);
        int idx = e0 + lane;
        int2 p = (idx < end) ? cpack[idx] : make_int2(0, 0);
        int cc = p.x;
        float vv = __int_as_float(p.y);
        int sp = (m + 1) >> 1;
#pragma unroll 4
        for (int s = 0; s < sp; s++) {
            int c0 = __shfl(cc, 2 * s), c1 = __shfl(cc, 2 * s + 1);
            float v0 = __shfl(vv, 2 * s), v1 = __shfl(vv, 2 * s + 1);
            int c = half ? c1 : c0;
            float v = half ? v1 : v0;
            u16x8 sv = *(const u16x8*)(base + (size_t)c * HID);
#pragma unroll
            for (int j = 0; j < 8; j++) acc[j] += v * bf2f(sv[j]);
        }
    }
#pragma unroll
    for (int j = 0; j < 8; j++) acc[j] += __shfl_xor(acc[j], 32);
    if (lane < 32) {
        float4 ba = *(const float4*)&b1[f8];
        float4 bb = *(const float4*)&b1[f8 + 4];
        u16x8 o;
        o[0] = f2bf(fmaxf(acc[0] + ba.x, 0.f));
        o[1] = f2bf(fmaxf(acc[1] + ba.y, 0.f));
        o[2] = f2bf(fmaxf(acc[2] + ba.z, 0.f));
        o[3] = f2bf(fmaxf(acc[3] + ba.w, 0.f));
        o[4] = f2bf(fmaxf(acc[4] + bb.x, 0.f));
        o[5] = f2bf(fmaxf(acc[5] + bb.y, 0.f));
        o[6] = f2bf(fmaxf(acc[6] + bb.z, 0.f));
        o[7] = f2bf(fmaxf(acc[7] + bb.w, 0.f));
        *(u16x8*)&Hb[(size_t)row * HID + f8] = o;
    }
}

// ---------------- GEMM2 (MFMA): S2(bf16) = h(bf16) @ W2t ----------------
// 64 rows/block, 4 waves (16 rows each), N=64 (40 real), K=256.
// A staged in LDS (each thread stages 64 contiguous u16 = 8 x int4);
// B read from L2-hot 32KB W2t.

#define G2STR 264

__global__ __launch_bounds__(256) void k_gemm2(const u16* __restrict__ Hb,
                                               const u16* __restrict__ W2t,
                                               u16* __restrict__ S2b) {
    __shared__ u16 As[64 * G2STR];
    int tid = threadIdx.x;
    int base = blockIdx.x * 64;
    {
        int r = tid >> 2, c0 = (tid & 3) * 64;
        const u16* src = Hb + (size_t)(base + r) * HID + c0;
        bool ok = (base + r) < N_NODES;
#pragma unroll
        for (int q = 0; q < 8; q++) {
            int4 d = ok ? *(const int4*)(src + q * 8) : make_int4(0, 0, 0, 0);
            *(int4*)&As[r * G2STR + c0 + q * 8] = d;
        }
    }
    __syncthreads();
    int lane = tid & 63, wv = tid >> 6;
    int r16 = lane & 15, kg = lane >> 4;
    f32x4 acc[4];
#pragma unroll
    for (int nt = 0; nt < 4; nt++) acc[nt] = (f32x4){0.f, 0.f, 0.f, 0.f};
#pragma unroll
    for (int ks = 0; ks < 8; ks++) {
        bf16x8 a = *(const bf16x8*)&As[(wv * 16 + r16) * G2STR + ks * 32 + kg * 8];
#pragma unroll
        for (int nt = 0; nt < 4; nt++) {
            bf16x8 b = *(const bf16x8*)&W2t[(size_t)(nt * 16 + r16) * 256 + ks * 32 + kg * 8];
            acc[nt] = __builtin_amdgcn_mfma_f32_16x16x32_bf16(a, b, acc[nt], 0, 0, 0);
        }
    }
    int orow = base + wv * 16 + (lane >> 4) * 4;
#pragma unroll
    for (int nt = 0; nt < 4; nt++) {
        int c = nt * 16 + r16;
        if (c < C_OUT) {
#pragma unroll
            for (int j = 0; j < 4; j++) {
                int r = orow + j;
                if (r < N_NODES) S2b[(size_t)r * C_OUT + c] = f2bf(acc[nt][j]);
            }
        }
    }
}

// ---------------- SPMM2 + bias + softmax/log_softmax (fused) ----------------
// Wave per row; 6 edges per step: 10 lanes per edge, each lane dwordx2 = 4 classes.
// Per-wave LDS transpose of partials, then wave softmax on lanes 0..39.

__global__ __launch_bounds__(256) void k_spmm2(const u16* __restrict__ S2b,
                                               const int2* __restrict__ cpack,
                                               const int* __restrict__ row_off,
                                               const float* __restrict__ b2,
                                               float* __restrict__ out_ls,
                                               float* __restrict__ out_sm) {
    __shared__ float red[4][64][4];
    int tid = threadIdx.x;
    int lane = tid & 63, wv = tid >> 6;
    int row = blockIdx.x * 4 + wv;
    int beg = row_off[row], end = row_off[row + 1];
    int g = lane / 10;           // edge slot 0..5 (lanes 60-63 inactive)
    int cb = (lane % 10) * 4;    // class block
    bool act = lane < 60;
    float acc[4] = {};
    for (int e0 = beg; e0 < end; e0 += 64) {
        int m = min(64, end - e0);
        int idx = e0 + lane;
        int2 p = (idx < end) ? cpack[idx] : make_int2(0, 0);
        int cc = p.x;
        float vv = __int_as_float(p.y);
        int sp = (m + 5) / 6;
#pragma unroll 4
        for (int s = 0; s < sp; s++) {
            int e = 6 * s + g;
            int c = __shfl(cc, e & 63);     // e>=64 wraps; harmless (v forced 0)
            float v = __shfl(vv, e & 63);
            v = (act && e < m) ? v : 0.f;
            u16x4 sv = *(const u16x4*)(S2b + (size_t)c * C_OUT + cb);
            acc[0] += v * bf2f(sv.x);
            acc[1] += v * bf2f(sv.y);
            acc[2] += v * bf2f(sv.z);
            acc[3] += v * bf2f(sv.w);
        }
    }
#pragma unroll
    for (int j = 0; j < 4; j++) red[wv][lane][j] = acc[j];
    float v;
    if (lane < C_OUT) {
        int b = lane >> 2, j = lane & 3;
        float s = 0.f;
#pragma unroll
        for (int gg = 0; gg < 6; gg++) s += red[wv][b + 10 * gg][j];
        v = s + b2[lane];
    } else {
        v = -1e30f;
    }
    float mx = v;
    for (int s = 32; s; s >>= 1) mx = fmaxf(mx, __shfl_xor(mx, s));
    float e = (lane < C_OUT) ? __expf(v - mx) : 0.f;
    float sum = e;
    for (int s = 32; s; s >>= 1) sum += __shfl_xor(sum, s);
    float ls = v - mx - __logf(sum);
    float sm = e / sum;
    if (lane < C_OUT) {
        out_ls[(size_t)row * C_OUT + lane] = ls;
        out_sm[(size_t)row * C_OUT + lane] = sm;
    }
}

// ---------------- launch ----------------

extern "C" void kernel_launch(void* const* d_in, const int* in_sizes, int n_in,
                              void* d_out, int out_size, void* d_ws, size_t ws_size,
                              hipStream_t stream) {
    const float* x    = (const float*)d_in[0];
    const float* W1   = (const float*)d_in[1];
    const float* b1   = (const float*)d_in[2];
    const float* W2   = (const float*)d_in[3];
    const float* b2   = (const float*)d_in[4];
    const int*   erow = (const int*)d_in[5];
    const int*   ecol = (const int*)d_in[6];
    const float* eval = (const float*)d_in[7];
    float* out = (float*)d_out;

    char* w = (char*)d_ws;
    auto alloc = [&](size_t bytes) {
        char* p = w;
        w += (bytes + 255) & ~(size_t)255;
        return p;
    };
    u16*   support = (u16*)  alloc((size_t)N_NODES * HID * sizeof(u16));
    u16*   hbuf    = (u16*)  alloc((size_t)N_NODES * HID * sizeof(u16));
    int2*  cpack   = (int2*) alloc((size_t)N_EDGES * sizeof(int2));
    int*   row_off = (int*)  alloc((size_t)(N_NODES + 1) * sizeof(int));
    int*   counts  = (int*)  alloc((size_t)N_NODES * sizeof(int));
    int*   fill    = (int*)  alloc((size_t)N_NODES * sizeof(int));
    int*   bsum    = (int*)  alloc(4096);
    int*   bbase   = (int*)  alloc(4096);
    u16*   S2b     = (u16*)  alloc((size_t)N_NODES * C_OUT * sizeof(u16));
    u16*   W2t     = (u16*)  alloc((size_t)64 * 256 * sizeof(u16));
    // W1t (256KB) aliases S2b's buffer: needed only during gemm1, S2b written later.
    u16*   W1t     = (u16*)S2b;

    hipMemsetAsync(counts, 0, (size_t)N_NODES * sizeof(int), stream);
    hipMemsetAsync(fill,   0, (size_t)N_NODES * sizeof(int), stream);

    int EB = (N_EDGES + 255) / 256;  // 12500
    k_hist<<<EB, 256, 0, stream>>>(erow, counts);
    int NB = (N_NODES + 255) / 256;  // 391
    k_scan_block<<<NB, 256, 0, stream>>>(counts, bsum, N_NODES);
    k_scan_base<<<1, 64, 0, stream>>>(bsum, bbase, NB, row_off, N_NODES);
    k_scan_final<<<NB, 256, 0, stream>>>(counts, bbase, row_off, N_NODES);
    k_scatter<<<EB, 256, 0, stream>>>(erow, ecol, eval, row_off, fill, cpack);

    k_cvtW1<<<(F_IN * HID) / 256, 256, 0, stream>>>(W1, W1t);
    k_cvtW2<<<(64 * 256) / 256, 256, 0, stream>>>(W2, W2t);
    k_gemm1<<<(N_NODES + 127) / 128, 512, 0, stream>>>(x, W1t, support, N_NODES);
    k_spmm1<<<N_NODES / 4, 256, 0, stream>>>(support, cpack, row_off, b1, hbuf);
    k_gemm2<<<(N_NODES + 63) / 64, 256, 0, stream>>>(hbuf, W2t, S2b);
    k_spmm2<<<N_NODES / 4, 256, 0, stream>>>(S2b, cpack, row_off, b2,
                                             out, out + (size_t)N_NODES * C_OUT);
}

// Round 6
// 684.442 us; speedup vs baseline: 2.2011x; 1.0766x over previous
//
#include <hip/hip_runtime.h>
#include <hip/hip_bf16.h>

#define N_NODES 100000
#define N_EDGES 3200000
#define F_IN    512
#define HID     256
#define C_OUT   40

typedef unsigned short u16;
typedef __attribute__((ext_vector_type(4))) unsigned short u16x4;
typedef __attribute__((ext_vector_type(8))) unsigned short u16x8;
typedef __attribute__((ext_vector_type(8))) short bf16x8;
typedef __attribute__((ext_vector_type(4))) float f32x4;

__device__ __forceinline__ float bf2f(u16 u) {
    unsigned int x = ((unsigned int)u) << 16;
    return __uint_as_float(x);
}
__device__ __forceinline__ u16 f2bf(float f) {
    unsigned int x = __float_as_uint(f);
    return (u16)((x + 0x7fffu + ((x >> 16) & 1u)) >> 16);  // RNE
}
__device__ __forceinline__ unsigned int pk2(float lo, float hi) {
    return (unsigned int)f2bf(lo) | ((unsigned int)f2bf(hi) << 16);
}

// ---------------- CSR build ----------------

// hist also records each edge's within-row rank (returned by atomicAdd),
// so the scatter needs no atomics.
__global__ __launch_bounds__(256) void k_hist(const int* __restrict__ row,
                                              int* __restrict__ counts,
                                              int* __restrict__ rank) {
    int t = blockIdx.x * 256 + threadIdx.x;
    const int n4 = (N_EDGES + 3) >> 2;
#pragma unroll
    for (int u = 0; u < 4; u++) {
        int i = t + u * n4;
        if (i < N_EDGES) rank[i] = atomicAdd(&counts[row[i]], 1);
    }
}

__global__ void k_scan_block(const int* __restrict__ counts, int* __restrict__ bsum, int n) {
    int i = blockIdx.x * 256 + threadIdx.x;
    int v = (i < n) ? counts[i] : 0;
    for (int s = 32; s; s >>= 1) v += __shfl_xor(v, s);
    __shared__ int red[4];
    int lane = threadIdx.x & 63, wv = threadIdx.x >> 6;
    if (lane == 0) red[wv] = v;
    __syncthreads();
    if (threadIdx.x == 0) bsum[blockIdx.x] = red[0] + red[1] + red[2] + red[3];
}

__global__ void k_scan_base(const int* __restrict__ bsum, int* __restrict__ bbase,
                            int nb, int* __restrict__ row_off, int N) {
    if (threadIdx.x == 0 && blockIdx.x == 0) {
        int run = 0;
        for (int b = 0; b < nb; b++) { bbase[b] = run; run += bsum[b]; }
        row_off[N] = run;
    }
}

__global__ void k_scan_final(const int* __restrict__ counts, const int* __restrict__ bbase,
                             int* __restrict__ row_off, int n) {
    __shared__ int s[256];
    int tid = threadIdx.x;
    int i = blockIdx.x * 256 + tid;
    int v = (i < n) ? counts[i] : 0;
    s[tid] = v;
    __syncthreads();
    for (int off = 1; off < 256; off <<= 1) {
        int t = (tid >= off) ? s[tid - off] : 0;
        __syncthreads();
        s[tid] += t;
        __syncthreads();
    }
    if (i < n) row_off[i] = bbase[blockIdx.x] + s[tid] - v;  // exclusive
}

// Atomic-free scatter: pos = row_off[row] + rank. 4 independent chains/thread.
__global__ __launch_bounds__(256) void k_scatter(const int* __restrict__ row,
                                                 const int* __restrict__ col,
                                                 const float* __restrict__ val,
                                                 const int* __restrict__ row_off,
                                                 const int* __restrict__ rank,
                                                 int2* __restrict__ cpack) {
    int t = blockIdx.x * 256 + threadIdx.x;
    const int n4 = (N_EDGES + 3) >> 2;
#pragma unroll
    for (int u = 0; u < 4; u++) {
        int i = t + u * n4;
        if (i < N_EDGES) {
            int pos = row_off[row[i]] + rank[i];
            cpack[pos] = make_int2(col[i], __float_as_int(val[i]));
        }
    }
}

// ---------------- weight converts ----------------

__global__ __launch_bounds__(256) void k_cvtW1(const float* __restrict__ W1,
                                               u16* __restrict__ W1t) {
    int i = blockIdx.x * 256 + threadIdx.x;  // over 512*256
    int k = i >> 8, n = i & 255;
    W1t[(size_t)n * F_IN + k] = f2bf(W1[i]);
}

// W2t: [64][256] bf16, classes 40..63 zero-padded.
__global__ __launch_bounds__(256) void k_cvtW2(const float* __restrict__ W2,
                                               u16* __restrict__ W2t) {
    int i = blockIdx.x * 256 + threadIdx.x;  // over 64*256
    int n = i >> 8, k = i & 255;
    W2t[i] = (n < C_OUT) ? f2bf(W2[k * C_OUT + n]) : (u16)0;
}

// ---------------- GEMM1 (MFMA): support(bf16) = x(f32) @ W1t ----------------

#define ASTR 40
#define BSTR 40

__global__ __launch_bounds__(512) void k_gemm1(const float* __restrict__ A,
                                               const u16* __restrict__ Bt,  // [256][512] bf16
                                               u16* __restrict__ Cb, int M) {
    __shared__ u16 As[2][128 * ASTR];
    __shared__ u16 Bs[2][256 * BSTR];
    int tid = threadIdx.x;
    int bm = blockIdx.x * 128;
    int lane = tid & 63, wid = tid >> 6;
    int wm = wid >> 2, wn = wid & 3;

    int s_ar = tid >> 2;
    int s_ak = (tid & 3) * 8;
    int s_bn = tid >> 1;
    int s_bk = (tid & 1) * 16;

    bool arow_ok = (bm + s_ar) < M;
    const float* aptr = A + (size_t)(bm + s_ar) * F_IN + s_ak;
    const u16*   bptr = Bt + (size_t)s_bn * F_IN + s_bk;

    f32x4 acc[4][4];
#pragma unroll
    for (int i = 0; i < 4; i++)
#pragma unroll
        for (int j = 0; j < 4; j++) acc[i][j] = (f32x4){0.f, 0.f, 0.f, 0.f};

    float4 ra0, ra1;
    int4 rb0, rb1;

    auto LOAD = [&](int kt) {
        const float* ap = aptr + kt * 32;
        if (arow_ok) {
            ra0 = *(const float4*)ap;
            ra1 = *(const float4*)(ap + 4);
        } else {
            ra0 = make_float4(0.f, 0.f, 0.f, 0.f);
            ra1 = ra0;
        }
        const u16* bp = bptr + kt * 32;
        rb0 = *(const int4*)bp;
        rb1 = *(const int4*)(bp + 8);
    };
    auto WRITE = [&](int buf) {
        int4 w;
        w.x = pk2(ra0.x, ra0.y);
        w.y = pk2(ra0.z, ra0.w);
        w.z = pk2(ra1.x, ra1.y);
        w.w = pk2(ra1.z, ra1.w);
        *(int4*)&As[buf][s_ar * ASTR + s_ak] = w;
        *(int4*)&Bs[buf][s_bn * BSTR + s_bk] = rb0;
        *(int4*)&Bs[buf][s_bn * BSTR + s_bk + 8] = rb1;
    };

    int kg = lane >> 4;
    int r16 = lane & 15;

    auto COMPUTE = [&](int buf) {
        bf16x8 a[4], b[4];
#pragma unroll
        for (int mt = 0; mt < 4; mt++)
            a[mt] = *(const bf16x8*)&As[buf][(wm * 64 + mt * 16 + r16) * ASTR + kg * 8];
#pragma unroll
        for (int nt = 0; nt < 4; nt++)
            b[nt] = *(const bf16x8*)&Bs[buf][(wn * 64 + nt * 16 + r16) * BSTR + kg * 8];
#pragma unroll
        for (int mt = 0; mt < 4; mt++)
#pragma unroll
            for (int nt = 0; nt < 4; nt++)
                acc[mt][nt] = __builtin_amdgcn_mfma_f32_16x16x32_bf16(
                    a[mt], b[nt], acc[mt][nt], 0, 0, 0);
    };

    LOAD(0);
    WRITE(0);
    __syncthreads();
#pragma unroll 1
    for (int kt = 0; kt < F_IN / 32; kt++) {
        int cur = kt & 1;
        if (kt < F_IN / 32 - 1) LOAD(kt + 1);
        COMPUTE(cur);
        if (kt < F_IN / 32 - 1) WRITE(cur ^ 1);
        __syncthreads();
    }

#pragma unroll
    for (int mt = 0; mt < 4; mt++) {
        int r0 = bm + wm * 64 + mt * 16 + (lane >> 4) * 4;
#pragma unroll
        for (int nt = 0; nt < 4; nt++) {
            int c = wn * 64 + nt * 16 + (lane & 15);
#pragma unroll
            for (int j = 0; j < 4; j++) {
                int r = r0 + j;
                if (r < M) Cb[(size_t)r * HID + c] = f2bf(acc[mt][nt][j]);
            }
        }
    }
}

// ---------------- SPMM1 + bias + relu: h(bf16) = A @ support(bf16) ----------------
// Wave per row. Edge stream is wave-uniform: beg/end via readfirstlane ->
// SGPR-batched edge loads (no shfl/bpermute). All 64 lanes cooperate on one
// edge: lane owns 4 features (8B dwordx2, SGPR-base + lane-offset). 8 edges
// batched for MLP.

__global__ __launch_bounds__(256) void k_spmm1(const u16* __restrict__ Sb,
                                               const int2* __restrict__ cpack,
                                               const int* __restrict__ row_off,
                                               const float* __restrict__ b1,
                                               u16* __restrict__ Hb) {
    int lane = threadIdx.x & 63;
    int row = blockIdx.x * 4 + (threadIdx.x >> 6);
    int beg = __builtin_amdgcn_readfirstlane(row_off[row]);
    int end = __builtin_amdgcn_readfirstlane(row_off[row + 1]);
    int f4 = lane * 4;
    const u16* base = Sb + f4;
    float acc[4] = {};
    int e = beg;
    for (; e + 8 <= end; e += 8) {
        int2 q[8];
#pragma unroll
        for (int t = 0; t < 8; t++) q[t] = cpack[e + t];
#pragma unroll
        for (int t = 0; t < 8; t++) {
            float vv = __int_as_float(q[t].y);
            u16x4 sv = *(const u16x4*)(base + (size_t)q[t].x * HID);
            acc[0] += vv * bf2f(sv.x);
            acc[1] += vv * bf2f(sv.y);
            acc[2] += vv * bf2f(sv.z);
            acc[3] += vv * bf2f(sv.w);
        }
    }
    for (; e < end; e++) {
        int2 q = cpack[e];
        float vv = __int_as_float(q.y);
        u16x4 sv = *(const u16x4*)(base + (size_t)q.x * HID);
        acc[0] += vv * bf2f(sv.x);
        acc[1] += vv * bf2f(sv.y);
        acc[2] += vv * bf2f(sv.z);
        acc[3] += vv * bf2f(sv.w);
    }
    float4 b = *(const float4*)&b1[f4];
    u16x4 o;
    o.x = f2bf(fmaxf(acc[0] + b.x, 0.f));
    o.y = f2bf(fmaxf(acc[1] + b.y, 0.f));
    o.z = f2bf(fmaxf(acc[2] + b.z, 0.f));
    o.w = f2bf(fmaxf(acc[3] + b.w, 0.f));
    *(u16x4*)&Hb[(size_t)row * HID + f4] = o;
}

// ---------------- GEMM2 (MFMA): S2(bf16) = h(bf16) @ W2t ----------------

#define G2STR 264

__global__ __launch_bounds__(256) void k_gemm2(const u16* __restrict__ Hb,
                                               const u16* __restrict__ W2t,
                                               u16* __restrict__ S2b) {
    __shared__ u16 As[64 * G2STR];
    int tid = threadIdx.x;
    int base = blockIdx.x * 64;
    {
        int r = tid >> 2, c0 = (tid & 3) * 64;
        const u16* src = Hb + (size_t)(base + r) * HID + c0;
        bool ok = (base + r) < N_NODES;
#pragma unroll
        for (int q = 0; q < 8; q++) {
            int4 d = ok ? *(const int4*)(src + q * 8) : make_int4(0, 0, 0, 0);
            *(int4*)&As[r * G2STR + c0 + q * 8] = d;
        }
    }
    __syncthreads();
    int lane = tid & 63, wv = tid >> 6;
    int r16 = lane & 15, kg = lane >> 4;
    f32x4 acc[4];
#pragma unroll
    for (int nt = 0; nt < 4; nt++) acc[nt] = (f32x4){0.f, 0.f, 0.f, 0.f};
#pragma unroll
    for (int ks = 0; ks < 8; ks++) {
        bf16x8 a = *(const bf16x8*)&As[(wv * 16 + r16) * G2STR + ks * 32 + kg * 8];
#pragma unroll
        for (int nt = 0; nt < 4; nt++) {
            bf16x8 b = *(const bf16x8*)&W2t[(size_t)(nt * 16 + r16) * 256 + ks * 32 + kg * 8];
            acc[nt] = __builtin_amdgcn_mfma_f32_16x16x32_bf16(a, b, acc[nt], 0, 0, 0);
        }
    }
    int orow = base + wv * 16 + (lane >> 4) * 4;
#pragma unroll
    for (int nt = 0; nt < 4; nt++) {
        int c = nt * 16 + r16;
        if (c < C_OUT) {
#pragma unroll
            for (int j = 0; j < 4; j++) {
                int r = orow + j;
                if (r < N_NODES) S2b[(size_t)r * C_OUT + c] = f2bf(acc[nt][j]);
            }
        }
    }
}

// ---------------- SPMM2 + bias + softmax/log_softmax (fused) ----------------
// Wave per row; lane = class (0..39). SGPR-batched edge loads; per edge one
// u16 gather per lane (80B/edge). No LDS.

__global__ __launch_bounds__(256) void k_spmm2(const u16* __restrict__ S2b,
                                               const int2* __restrict__ cpack,
                                               const int* __restrict__ row_off,
                                               const float* __restrict__ b2,
                                               float* __restrict__ out_ls,
                                               float* __restrict__ out_sm) {
    int lane = threadIdx.x & 63;
    int row = blockIdx.x * 4 + (threadIdx.x >> 6);
    int beg = __builtin_amdgcn_readfirstlane(row_off[row]);
    int end = __builtin_amdgcn_readfirstlane(row_off[row + 1]);
    int l = (lane < C_OUT) ? lane : 0;
    float acc = 0.f;
    int e = beg;
    for (; e + 8 <= end; e += 8) {
        int2 q[8];
#pragma unroll
        for (int t = 0; t < 8; t++) q[t] = cpack[e + t];
#pragma unroll
        for (int t = 0; t < 8; t++) {
            float vv = __int_as_float(q[t].y);
            u16 sv = S2b[(size_t)q[t].x * C_OUT + l];
            acc += vv * bf2f(sv);
        }
    }
    for (; e < end; e++) {
        int2 q = cpack[e];
        acc += __int_as_float(q.y) * bf2f(S2b[(size_t)q.x * C_OUT + l]);
    }
    float v = (lane < C_OUT) ? (acc + b2[l]) : -1e30f;
    float mx = v;
    for (int s = 32; s; s >>= 1) mx = fmaxf(mx, __shfl_xor(mx, s));
    float e2 = (lane < C_OUT) ? __expf(v - mx) : 0.f;
    float sum = e2;
    for (int s = 32; s; s >>= 1) sum += __shfl_xor(sum, s);
    float ls = v - mx - __logf(sum);
    float sm = e2 / sum;
    if (lane < C_OUT) {
        out_ls[(size_t)row * C_OUT + lane] = ls;
        out_sm[(size_t)row * C_OUT + lane] = sm;
    }
}

// ---------------- launch ----------------

extern "C" void kernel_launch(void* const* d_in, const int* in_sizes, int n_in,
                              void* d_out, int out_size, void* d_ws, size_t ws_size,
                              hipStream_t stream) {
    const float* x    = (const float*)d_in[0];
    const float* W1   = (const float*)d_in[1];
    const float* b1   = (const float*)d_in[2];
    const float* W2   = (const float*)d_in[3];
    const float* b2   = (const float*)d_in[4];
    const int*   erow = (const int*)d_in[5];
    const int*   ecol = (const int*)d_in[6];
    const float* eval = (const float*)d_in[7];
    float* out = (float*)d_out;

    char* w = (char*)d_ws;
    auto alloc = [&](size_t bytes) {
        char* p = w;
        w += (bytes + 255) & ~(size_t)255;
        return p;
    };
    u16*   support = (u16*)  alloc((size_t)N_NODES * HID * sizeof(u16));
    u16*   hbuf    = (u16*)  alloc((size_t)N_NODES * HID * sizeof(u16));
    int2*  cpack   = (int2*) alloc((size_t)N_EDGES * sizeof(int2));
    int*   row_off = (int*)  alloc((size_t)(N_NODES + 1) * sizeof(int));
    int*   counts  = (int*)  alloc((size_t)N_NODES * sizeof(int));
    int*   bsum    = (int*)  alloc(4096);
    int*   bbase   = (int*)  alloc(4096);
    u16*   S2b     = (u16*)  alloc((size_t)N_NODES * C_OUT * sizeof(u16));
    u16*   W2t     = (u16*)  alloc((size_t)64 * 256 * sizeof(u16));
    // rank (12.8MB) aliases hbuf (51MB): rank used only before spmm1 writes hbuf.
    int*   rank    = (int*)hbuf;
    // W1t (256KB) aliases S2b: needed only during gemm1, S2b written later.
    u16*   W1t     = (u16*)S2b;

    hipMemsetAsync(counts, 0, (size_t)N_NODES * sizeof(int), stream);

    const int n4 = (N_EDGES + 3) >> 2;
    int EB4 = (n4 + 255) / 256;  // 3125
    k_hist<<<EB4, 256, 0, stream>>>(erow, counts, rank);
    int NB = (N_NODES + 255) / 256;  // 391
    k_scan_block<<<NB, 256, 0, stream>>>(counts, bsum, N_NODES);
    k_scan_base<<<1, 64, 0, stream>>>(bsum, bbase, NB, row_off, N_NODES);
    k_scan_final<<<NB, 256, 0, stream>>>(counts, bbase, row_off, N_NODES);
    k_scatter<<<EB4, 256, 0, stream>>>(erow, ecol, eval, row_off, rank, cpack);

    k_cvtW1<<<(F_IN * HID) / 256, 256, 0, stream>>>(W1, W1t);
    k_cvtW2<<<(64 * 256) / 256, 256, 0, stream>>>(W2, W2t);
    k_gemm1<<<(N_NODES + 127) / 128, 512, 0, stream>>>(x, W1t, support, N_NODES);
    k_spmm1<<<N_NODES / 4, 256, 0, stream>>>(support, cpack, row_off, b1, hbuf);
    k_gemm2<<<(N_NODES + 63) / 64, 256, 0, stream>>>(hbuf, W2t, S2b);
    k_spmm2<<<N_NODES / 4, 256, 0, stream>>>(S2b, cpack, row_off, b2,
                                             out, out + (size_t)N_NODES * C_OUT);
}

// Round 7
// 557.852 us; speedup vs baseline: 2.7005x; 1.2269x over previous
//
#include <hip/hip_runtime.h>
#include <hip/hip_bf16.h>

#define N_NODES 100000
#define N_EDGES 3200000
#define F_IN    512
#define HID     256
#define C_OUT   40

typedef unsigned short u16;
typedef unsigned char  u8;
typedef __attribute__((ext_vector_type(4))) unsigned short u16x4;
typedef __attribute__((ext_vector_type(8))) short bf16x8;
typedef __attribute__((ext_vector_type(4))) float f32x4;
typedef __attribute__((ext_vector_type(2))) float f32x2;

__device__ __forceinline__ float bf2f(u16 u) {
    unsigned int x = ((unsigned int)u) << 16;
    return __uint_as_float(x);
}
__device__ __forceinline__ u16 f2bf(float f) {
    unsigned int x = __float_as_uint(f);
    return (u16)((x + 0x7fffu + ((x >> 16) & 1u)) >> 16);  // RNE
}
__device__ __forceinline__ unsigned int pk2(float lo, float hi) {
    return (unsigned int)f2bf(lo) | ((unsigned int)f2bf(hi) << 16);
}
__device__ __forceinline__ u8 f2fp8(float f) {  // OCP e4m3, HW RNE
    return (u8)(__builtin_amdgcn_cvt_pk_fp8_f32(f, f, 0u, false) & 0xFF);
}

// ---------------- CSR build ----------------

// hist also records each edge's within-row rank (returned by atomicAdd),
// so the scatter needs no atomics.
__global__ __launch_bounds__(256) void k_hist(const int* __restrict__ row,
                                              int* __restrict__ counts,
                                              int* __restrict__ rank) {
    int t = blockIdx.x * 256 + threadIdx.x;
    const int n4 = (N_EDGES + 3) >> 2;
#pragma unroll
    for (int u = 0; u < 4; u++) {
        int i = t + u * n4;
        if (i < N_EDGES) rank[i] = atomicAdd(&counts[row[i]], 1);
    }
}

__global__ void k_scan_block(const int* __restrict__ counts, int* __restrict__ bsum, int n) {
    int i = blockIdx.x * 256 + threadIdx.x;
    int v = (i < n) ? counts[i] : 0;
    for (int s = 32; s; s >>= 1) v += __shfl_xor(v, s);
    __shared__ int red[4];
    int lane = threadIdx.x & 63, wv = threadIdx.x >> 6;
    if (lane == 0) red[wv] = v;
    __syncthreads();
    if (threadIdx.x == 0) bsum[blockIdx.x] = red[0] + red[1] + red[2] + red[3];
}

__global__ void k_scan_base(const int* __restrict__ bsum, int* __restrict__ bbase,
                            int nb, int* __restrict__ row_off, int N) {
    if (threadIdx.x == 0 && blockIdx.x == 0) {
        int run = 0;
        for (int b = 0; b < nb; b++) { bbase[b] = run; run += bsum[b]; }
        row_off[N] = run;
    }
}

__global__ void k_scan_final(const int* __restrict__ counts, const int* __restrict__ bbase,
                             int* __restrict__ row_off, int n) {
    __shared__ int s[256];
    int tid = threadIdx.x;
    int i = blockIdx.x * 256 + tid;
    int v = (i < n) ? counts[i] : 0;
    s[tid] = v;
    __syncthreads();
    for (int off = 1; off < 256; off <<= 1) {
        int t = (tid >= off) ? s[tid - off] : 0;
        __syncthreads();
        s[tid] += t;
        __syncthreads();
    }
    if (i < n) row_off[i] = bbase[blockIdx.x] + s[tid] - v;  // exclusive
}

// Atomic-free scatter: pos = row_off[row] + rank. 4 independent chains/thread.
__global__ __launch_bounds__(256) void k_scatter(const int* __restrict__ row,
                                                 const int* __restrict__ col,
                                                 const float* __restrict__ val,
                                                 const int* __restrict__ row_off,
                                                 const int* __restrict__ rank,
                                                 int2* __restrict__ cpack) {
    int t = blockIdx.x * 256 + threadIdx.x;
    const int n4 = (N_EDGES + 3) >> 2;
#pragma unroll
    for (int u = 0; u < 4; u++) {
        int i = t + u * n4;
        if (i < N_EDGES) {
            int pos = row_off[row[i]] + rank[i];
            cpack[pos] = make_int2(col[i], __float_as_int(val[i]));
        }
    }
}

// ---------------- weight converts ----------------

__global__ __launch_bounds__(256) void k_cvtW1(const float* __restrict__ W1,
                                               u16* __restrict__ W1t) {
    int i = blockIdx.x * 256 + threadIdx.x;  // over 512*256
    int k = i >> 8, n = i & 255;
    W1t[(size_t)n * F_IN + k] = f2bf(W1[i]);
}

// W2t: [64][256] bf16, classes 40..63 zero-padded.
__global__ __launch_bounds__(256) void k_cvtW2(const float* __restrict__ W2,
                                               u16* __restrict__ W2t) {
    int i = blockIdx.x * 256 + threadIdx.x;  // over 64*256
    int n = i >> 8, k = i & 255;
    W2t[i] = (n < C_OUT) ? f2bf(W2[k * C_OUT + n]) : (u16)0;
}

// ---------------- GEMM1 (MFMA): support(fp8) = x(f32) @ W1t ----------------

#define ASTR 40
#define BSTR 40

__global__ __launch_bounds__(512) void k_gemm1(const float* __restrict__ A,
                                               const u16* __restrict__ Bt,  // [256][512] bf16
                                               u8* __restrict__ Cf8, int M) {
    __shared__ u16 As[2][128 * ASTR];
    __shared__ u16 Bs[2][256 * BSTR];
    int tid = threadIdx.x;
    int bm = blockIdx.x * 128;
    int lane = tid & 63, wid = tid >> 6;
    int wm = wid >> 2, wn = wid & 3;

    int s_ar = tid >> 2;
    int s_ak = (tid & 3) * 8;
    int s_bn = tid >> 1;
    int s_bk = (tid & 1) * 16;

    bool arow_ok = (bm + s_ar) < M;
    const float* aptr = A + (size_t)(bm + s_ar) * F_IN + s_ak;
    const u16*   bptr = Bt + (size_t)s_bn * F_IN + s_bk;

    f32x4 acc[4][4];
#pragma unroll
    for (int i = 0; i < 4; i++)
#pragma unroll
        for (int j = 0; j < 4; j++) acc[i][j] = (f32x4){0.f, 0.f, 0.f, 0.f};

    float4 ra0, ra1;
    int4 rb0, rb1;

    auto LOAD = [&](int kt) {
        const float* ap = aptr + kt * 32;
        if (arow_ok) {
            ra0 = *(const float4*)ap;
            ra1 = *(const float4*)(ap + 4);
        } else {
            ra0 = make_float4(0.f, 0.f, 0.f, 0.f);
            ra1 = ra0;
        }
        const u16* bp = bptr + kt * 32;
        rb0 = *(const int4*)bp;
        rb1 = *(const int4*)(bp + 8);
    };
    auto WRITE = [&](int buf) {
        int4 w;
        w.x = pk2(ra0.x, ra0.y);
        w.y = pk2(ra0.z, ra0.w);
        w.z = pk2(ra1.x, ra1.y);
        w.w = pk2(ra1.z, ra1.w);
        *(int4*)&As[buf][s_ar * ASTR + s_ak] = w;
        *(int4*)&Bs[buf][s_bn * BSTR + s_bk] = rb0;
        *(int4*)&Bs[buf][s_bn * BSTR + s_bk + 8] = rb1;
    };

    int kg = lane >> 4;
    int r16 = lane & 15;

    auto COMPUTE = [&](int buf) {
        bf16x8 a[4], b[4];
#pragma unroll
        for (int mt = 0; mt < 4; mt++)
            a[mt] = *(const bf16x8*)&As[buf][(wm * 64 + mt * 16 + r16) * ASTR + kg * 8];
#pragma unroll
        for (int nt = 0; nt < 4; nt++)
            b[nt] = *(const bf16x8*)&Bs[buf][(wn * 64 + nt * 16 + r16) * BSTR + kg * 8];
#pragma unroll
        for (int mt = 0; mt < 4; mt++)
#pragma unroll
            for (int nt = 0; nt < 4; nt++)
                acc[mt][nt] = __builtin_amdgcn_mfma_f32_16x16x32_bf16(
                    a[mt], b[nt], acc[mt][nt], 0, 0, 0);
    };

    LOAD(0);
    WRITE(0);
    __syncthreads();
#pragma unroll 1
    for (int kt = 0; kt < F_IN / 32; kt++) {
        int cur = kt & 1;
        if (kt < F_IN / 32 - 1) LOAD(kt + 1);
        COMPUTE(cur);
        if (kt < F_IN / 32 - 1) WRITE(cur ^ 1);
        __syncthreads();
    }

#pragma unroll
    for (int mt = 0; mt < 4; mt++) {
        int r0 = bm + wm * 64 + mt * 16 + (lane >> 4) * 4;
#pragma unroll
        for (int nt = 0; nt < 4; nt++) {
            int c = wn * 64 + nt * 16 + (lane & 15);
#pragma unroll
            for (int j = 0; j < 4; j++) {
                int r = r0 + j;
                if (r < M) Cf8[(size_t)r * HID + c] = f2fp8(acc[mt][nt][j]);
            }
        }
    }
}

// ---------------- SPMM1 + bias + relu: h(bf16) = A @ support(fp8) ----------------
// Wave per row; SGPR-uniform edge loads (batch 8); all 64 lanes on one edge:
// lane owns 4 features = one dword gather, HW fp8->f32 decode.

__global__ __launch_bounds__(256) void k_spmm1(const u8* __restrict__ Sf8,
                                               const int2* __restrict__ cpack,
                                               const int* __restrict__ row_off,
                                               const float* __restrict__ b1,
                                               u16* __restrict__ Hb) {
    int lane = threadIdx.x & 63;
    int row = blockIdx.x * 4 + (threadIdx.x >> 6);
    int beg = __builtin_amdgcn_readfirstlane(row_off[row]);
    int end = __builtin_amdgcn_readfirstlane(row_off[row + 1]);
    int f4 = lane * 4;
    const u8* base = Sf8 + f4;
    float acc[4] = {};
    int e = beg;
    for (; e + 8 <= end; e += 8) {
        int2 q[8];
#pragma unroll
        for (int t = 0; t < 8; t++) q[t] = cpack[e + t];
#pragma unroll
        for (int t = 0; t < 8; t++) {
            float vv = __int_as_float(q[t].y);
            unsigned int w = *(const unsigned int*)(base + (size_t)q[t].x * HID);
            f32x2 lo = __builtin_amdgcn_cvt_pk_f32_fp8(w, false);
            f32x2 hi = __builtin_amdgcn_cvt_pk_f32_fp8(w, true);
            acc[0] += vv * lo.x;
            acc[1] += vv * lo.y;
            acc[2] += vv * hi.x;
            acc[3] += vv * hi.y;
        }
    }
    for (; e < end; e++) {
        int2 q = cpack[e];
        float vv = __int_as_float(q.y);
        unsigned int w = *(const unsigned int*)(base + (size_t)q.x * HID);
        f32x2 lo = __builtin_amdgcn_cvt_pk_f32_fp8(w, false);
        f32x2 hi = __builtin_amdgcn_cvt_pk_f32_fp8(w, true);
        acc[0] += vv * lo.x;
        acc[1] += vv * lo.y;
        acc[2] += vv * hi.x;
        acc[3] += vv * hi.y;
    }
    float4 b = *(const float4*)&b1[f4];
    u16x4 o;
    o.x = f2bf(fmaxf(acc[0] + b.x, 0.f));
    o.y = f2bf(fmaxf(acc[1] + b.y, 0.f));
    o.z = f2bf(fmaxf(acc[2] + b.z, 0.f));
    o.w = f2bf(fmaxf(acc[3] + b.w, 0.f));
    *(u16x4*)&Hb[(size_t)row * HID + f4] = o;
}

// ---------------- GEMM2 (MFMA): S2(fp8) = h(bf16) @ W2t ----------------

#define G2STR 264

__global__ __launch_bounds__(256) void k_gemm2(const u16* __restrict__ Hb,
                                               const u16* __restrict__ W2t,
                                               u8* __restrict__ S2f8) {
    __shared__ u16 As[64 * G2STR];
    int tid = threadIdx.x;
    int base = blockIdx.x * 64;
    {
        int r = tid >> 2, c0 = (tid & 3) * 64;
        const u16* src = Hb + (size_t)(base + r) * HID + c0;
        bool ok = (base + r) < N_NODES;
#pragma unroll
        for (int q = 0; q < 8; q++) {
            int4 d = ok ? *(const int4*)(src + q * 8) : make_int4(0, 0, 0, 0);
            *(int4*)&As[r * G2STR + c0 + q * 8] = d;
        }
    }
    __syncthreads();
    int lane = tid & 63, wv = tid >> 6;
    int r16 = lane & 15, kg = lane >> 4;
    f32x4 acc[4];
#pragma unroll
    for (int nt = 0; nt < 4; nt++) acc[nt] = (f32x4){0.f, 0.f, 0.f, 0.f};
#pragma unroll
    for (int ks = 0; ks < 8; ks++) {
        bf16x8 a = *(const bf16x8*)&As[(wv * 16 + r16) * G2STR + ks * 32 + kg * 8];
#pragma unroll
        for (int nt = 0; nt < 4; nt++) {
            bf16x8 b = *(const bf16x8*)&W2t[(size_t)(nt * 16 + r16) * 256 + ks * 32 + kg * 8];
            acc[nt] = __builtin_amdgcn_mfma_f32_16x16x32_bf16(a, b, acc[nt], 0, 0, 0);
        }
    }
    int orow = base + wv * 16 + (lane >> 4) * 4;
#pragma unroll
    for (int nt = 0; nt < 4; nt++) {
        int c = nt * 16 + r16;
        if (c < C_OUT) {
#pragma unroll
            for (int j = 0; j < 4; j++) {
                int r = orow + j;
                if (r < N_NODES) S2f8[(size_t)r * C_OUT + c] = f2fp8(acc[nt][j]);
            }
        }
    }
}

// ---------------- SPMM2 + bias + softmax/log_softmax (fused) ----------------
// Wave per row; lane = class (0..39); S2 is fp8 (4MB, L2-resident).

__global__ __launch_bounds__(256) void k_spmm2(const u8* __restrict__ S2f8,
                                               const int2* __restrict__ cpack,
                                               const int* __restrict__ row_off,
                                               const float* __restrict__ b2,
                                               float* __restrict__ out_ls,
                                               float* __restrict__ out_sm) {
    int lane = threadIdx.x & 63;
    int row = blockIdx.x * 4 + (threadIdx.x >> 6);
    int beg = __builtin_amdgcn_readfirstlane(row_off[row]);
    int end = __builtin_amdgcn_readfirstlane(row_off[row + 1]);
    int l = (lane < C_OUT) ? lane : 0;
    float acc = 0.f;
    int e = beg;
    for (; e + 8 <= end; e += 8) {
        int2 q[8];
#pragma unroll
        for (int t = 0; t < 8; t++) q[t] = cpack[e + t];
#pragma unroll
        for (int t = 0; t < 8; t++) {
            float vv = __int_as_float(q[t].y);
            unsigned int sv = S2f8[(size_t)q[t].x * C_OUT + l];
            acc += vv * __builtin_amdgcn_cvt_f32_fp8(sv, 0);
        }
    }
    for (; e < end; e++) {
        int2 q = cpack[e];
        unsigned int sv = S2f8[(size_t)q.x * C_OUT + l];
        acc += __int_as_float(q.y) * __builtin_amdgcn_cvt_f32_fp8(sv, 0);
    }
    float v = (lane < C_OUT) ? (acc + b2[l]) : -1e30f;
    float mx = v;
    for (int s = 32; s; s >>= 1) mx = fmaxf(mx, __shfl_xor(mx, s));
    float e2 = (lane < C_OUT) ? __expf(v - mx) : 0.f;
    float sum = e2;
    for (int s = 32; s; s >>= 1) sum += __shfl_xor(sum, s);
    float ls = v - mx - __logf(sum);
    float sm = e2 / sum;
    if (lane < C_OUT) {
        out_ls[(size_t)row * C_OUT + lane] = ls;
        out_sm[(size_t)row * C_OUT + lane] = sm;
    }
}

// ---------------- launch ----------------

extern "C" void kernel_launch(void* const* d_in, const int* in_sizes, int n_in,
                              void* d_out, int out_size, void* d_ws, size_t ws_size,
                              hipStream_t stream) {
    const float* x    = (const float*)d_in[0];
    const float* W1   = (const float*)d_in[1];
    const float* b1   = (const float*)d_in[2];
    const float* W2   = (const float*)d_in[3];
    const float* b2   = (const float*)d_in[4];
    const int*   erow = (const int*)d_in[5];
    const int*   ecol = (const int*)d_in[6];
    const float* eval = (const float*)d_in[7];
    float* out = (float*)d_out;

    char* w = (char*)d_ws;
    auto alloc = [&](size_t bytes) {
        char* p = w;
        w += (bytes + 255) & ~(size_t)255;
        return p;
    };
    u8*    support = (u8*)   alloc((size_t)N_NODES * HID);               // fp8
    u16*   hbuf    = (u16*)  alloc((size_t)N_NODES * HID * sizeof(u16)); // bf16
    int2*  cpack   = (int2*) alloc((size_t)N_EDGES * sizeof(int2));
    int*   row_off = (int*)  alloc((size_t)(N_NODES + 1) * sizeof(int));
    int*   counts  = (int*)  alloc((size_t)N_NODES * sizeof(int));
    int*   bsum    = (int*)  alloc(4096);
    int*   bbase   = (int*)  alloc(4096);
    u8*    S2f8    = (u8*)   alloc((size_t)N_NODES * C_OUT);             // fp8
    u16*   W2t     = (u16*)  alloc((size_t)64 * 256 * sizeof(u16));
    u16*   W1t     = (u16*)  alloc((size_t)F_IN * HID * sizeof(u16));
    // rank (12.8MB) aliases hbuf (51MB): rank used only before spmm1 writes hbuf.
    int*   rank    = (int*)hbuf;

    hipMemsetAsync(counts, 0, (size_t)N_NODES * sizeof(int), stream);

    const int n4 = (N_EDGES + 3) >> 2;
    int EB4 = (n4 + 255) / 256;  // 3125
    k_hist<<<EB4, 256, 0, stream>>>(erow, counts, rank);
    int NB = (N_NODES + 255) / 256;  // 391
    k_scan_block<<<NB, 256, 0, stream>>>(counts, bsum, N_NODES);
    k_scan_base<<<1, 64, 0, stream>>>(bsum, bbase, NB, row_off, N_NODES);
    k_scan_final<<<NB, 256, 0, stream>>>(counts, bbase, row_off, N_NODES);
    k_scatter<<<EB4, 256, 0, stream>>>(erow, ecol, eval, row_off, rank, cpack);

    k_cvtW1<<<(F_IN * HID) / 256, 256, 0, stream>>>(W1, W1t);
    k_cvtW2<<<(64 * 256) / 256, 256, 0, stream>>>(W2, W2t);
    k_gemm1<<<(N_NODES + 127) / 128, 512, 0, stream>>>(x, W1t, support, N_NODES);
    k_spmm1<<<N_NODES / 4, 256, 0, stream>>>(support, cpack, row_off, b1, hbuf);
    k_gemm2<<<(N_NODES + 63) / 64, 256, 0, stream>>>(hbuf, W2t, S2f8);
    k_spmm2<<<N_NODES / 4, 256, 0, stream>>>(S2f8, cpack, row_off, b2,
                                             out, out + (size_t)N_NODES * C_OUT);
}